// Round 5
// baseline (915.182 us; speedup 1.0000x reference)
//
#include <hip/hip_runtime.h>
#include <hip/hip_bf16.h>
#include <math.h>

#define NN 50000
#define EE 600000
#define DIM 128
#define LL 3

__device__ __forceinline__ float gelu_f(float x) {
    return 0.5f * x * (1.0f + erff(x * 0.70710678118654752440f));
}

// ---------------- CSR build ----------------
__global__ __launch_bounds__(256) void deg_kernel(const int* __restrict__ dst,
                                                  int* __restrict__ deg) {
    int e = blockIdx.x * blockDim.x + threadIdx.x;
    if (e < EE) atomicAdd(&deg[dst[e]], 1);
}

// Single-block exclusive scan of deg -> rowptr[0..N], cursor = rowptr, invdeg.
__global__ __launch_bounds__(1024)
void scan_kernel(const int* __restrict__ deg, int* __restrict__ rowptr,
                 int* __restrict__ cursor, float* __restrict__ invdeg) {
    __shared__ int part[1024];
    const int t = threadIdx.x;
    const int CH = (NN + 1023) / 1024;  // 49
    const int lo = t * CH;
    const int hi = (lo + CH < NN) ? lo + CH : NN;
    int s = 0;
    for (int i = lo; i < hi; ++i) s += deg[i];
    part[t] = s;
    __syncthreads();
    for (int off = 1; off < 1024; off <<= 1) {
        int v = part[t];
        int add = (t >= off) ? part[t - off] : 0;
        __syncthreads();
        part[t] = v + add;
        __syncthreads();
    }
    int base = (t == 0) ? 0 : part[t - 1];
    for (int i = lo; i < hi; ++i) {
        int d = deg[i];
        rowptr[i] = base;
        cursor[i] = base;
        invdeg[i] = 1.0f / (float)(d < 1 ? 1 : d);
        base += d;
    }
    if (t == 1023) rowptr[NN] = base;  // == EE
}

// Bucket edges by dst; store src id directly (no second indirection later).
__global__ __launch_bounds__(256)
void bucket_kernel(const int* __restrict__ src, const int* __restrict__ dst,
                   int* __restrict__ cursor, int* __restrict__ ebuf) {
    int e = blockIdx.x * blockDim.x + threadIdx.x;
    if (e < EE) {
        int slot = atomicAdd(&cursor[dst[e]], 1);
        ebuf[slot] = src[e];
    }
}

// ---------------- CSR gather aggregation ----------------
// One 64-lane wave per dst node; lane owns 2 columns (float2).
// agg may alias qry: each wave loads its own qry row into registers before
// storing agg to the same row, and no other wave touches that row.
__global__ __launch_bounds__(256)
void agg_kernel(const float* __restrict__ key, const float* __restrict__ qry,
                const int* __restrict__ rowptr, const int* __restrict__ ebuf,
                const float* __restrict__ invdeg, float* __restrict__ agg) {
    int tid = blockIdx.x * blockDim.x + threadIdx.x;
    int n = tid >> 6;
    if (n >= NN) return;
    int c = (tid & 63) << 1;
    const float2 q2 = *(const float2*)(qry + (size_t)n * DIM + c);
    float ax = 0.f, ay = 0.f;
    const int lo = rowptr[n], hi = rowptr[n + 1];
    for (int j = lo; j < hi; ++j) {
        const int s = ebuf[j];
        const float2 k2 = *(const float2*)(key + (size_t)s * DIM + c);
        ax += gelu_f(k2.x + q2.x);
        ay += gelu_f(k2.y + q2.y);
    }
    const float inv = invdeg[n];
    *(float2*)(agg + (size_t)n * DIM + c) = make_float2(ax * inv, ay * inv);
}

// ---------------- GEMM: C[M,128] = epi(A[M,128] @ W[128,128] + bias) ----------------
enum { EPI_NONE = 0, EPI_GELU = 1, EPI_RESID = 2 };

template <int EPI>
__global__ __launch_bounds__(256)
void gemm128(const float* __restrict__ A, const float* __restrict__ W,
             const float* __restrict__ bias, const float* __restrict__ resid,
             float* __restrict__ C, int M) {
    constexpr int BM = 64, KC = 32, AP = KC + 4;  // AP pad -> 2-way LDS alias (free)
    __shared__ float As[BM][AP];      // 9.2 KB
    __shared__ float Ws[KC][DIM];     // 16 KB
    const int t = threadIdx.x;
    const int row0 = blockIdx.x * BM;
    const int tc = t & 15;   // 16 col groups; cols {tc*4..+3} and {64+tc*4..+3}
    const int tr = t >> 4;   // 16 row groups of 4 rows

    float acc[4][8];
#pragma unroll
    for (int i = 0; i < 4; ++i)
#pragma unroll
        for (int j = 0; j < 8; ++j) acc[i][j] = 0.f;

    for (int k0 = 0; k0 < DIM; k0 += KC) {
        // ---- stage A chunk (64 x 32) ----
        {
            const int r = t >> 2;
            const int c = (t & 3) << 3;
            const int grow = row0 + r;
            float4 v0 = make_float4(0.f, 0.f, 0.f, 0.f), v1 = v0;
            if (grow < M) {
                const float* p = A + (size_t)grow * DIM + k0 + c;
                v0 = *(const float4*)p;
                v1 = *(const float4*)(p + 4);
            }
            *(float4*)&As[r][c] = v0;
            *(float4*)&As[r][c + 4] = v1;
        }
        // ---- stage W chunk (32 x 128), fully coalesced flat copy ----
        {
            const float4* gp = (const float4*)(W + (size_t)k0 * DIM);
            float4* sp = (float4*)&Ws[0][0];
#pragma unroll
            for (int i = 0; i < 4; ++i) sp[i * 256 + t] = gp[i * 256 + t];
        }
        __syncthreads();
#pragma unroll
        for (int kk = 0; kk < KC; kk += 4) {
            float4 a[4];
#pragma unroll
            for (int r = 0; r < 4; ++r)
                a[r] = *(const float4*)&As[tr * 4 + r][kk];
            float4 b[4][2];
#pragma unroll
            for (int k = 0; k < 4; ++k) {
                b[k][0] = *(const float4*)&Ws[kk + k][tc * 4];
                b[k][1] = *(const float4*)&Ws[kk + k][64 + tc * 4];
            }
#pragma unroll
            for (int r = 0; r < 4; ++r) {
                const float ar[4] = {a[r].x, a[r].y, a[r].z, a[r].w};
#pragma unroll
                for (int k = 0; k < 4; ++k) {
                    acc[r][0] += ar[k] * b[k][0].x;
                    acc[r][1] += ar[k] * b[k][0].y;
                    acc[r][2] += ar[k] * b[k][0].z;
                    acc[r][3] += ar[k] * b[k][0].w;
                    acc[r][4] += ar[k] * b[k][1].x;
                    acc[r][5] += ar[k] * b[k][1].y;
                    acc[r][6] += ar[k] * b[k][1].z;
                    acc[r][7] += ar[k] * b[k][1].w;
                }
            }
        }
        __syncthreads();
    }
    // ---- epilogue ----
    const int c0 = tc * 4;
    float bs[8];
#pragma unroll
    for (int j = 0; j < 4; ++j) {
        bs[j] = bias[c0 + j];
        bs[j + 4] = bias[64 + c0 + j];
    }
#pragma unroll
    for (int r = 0; r < 4; ++r) {
        const int grow = row0 + tr * 4 + r;
        if (grow < M) {
            float o[8];
#pragma unroll
            for (int j = 0; j < 8; ++j) o[j] = acc[r][j] + bs[j];
            if (EPI == EPI_GELU) {
#pragma unroll
                for (int j = 0; j < 8; ++j) o[j] = gelu_f(o[j]);
            }
            if (EPI == EPI_RESID) {
                const float* rp = resid + (size_t)grow * DIM;
#pragma unroll
                for (int j = 0; j < 4; ++j) {
                    o[j] += rp[c0 + j];
                    o[j + 4] += rp[64 + c0 + j];
                }
            }
            float* cp = C + (size_t)grow * DIM;
            *(float4*)(cp + c0) = make_float4(o[0], o[1], o[2], o[3]);
            *(float4*)(cp + 64 + c0) = make_float4(o[4], o[5], o[6], o[7]);
        }
    }
}

// ---------------- fused K/Q GEMM: K = A@Wk+bk, Q = A@Wq+bq (one A staging) ----
__global__ __launch_bounds__(256)
void gemm128_kq(const float* __restrict__ A,
                const float* __restrict__ Wkw, const float* __restrict__ bkw,
                const float* __restrict__ Wqw, const float* __restrict__ bqw,
                float* __restrict__ K, float* __restrict__ Q, int M) {
    constexpr int BM = 64, KC = 32, AP = KC + 4;
    __shared__ float As[BM][AP];       // 9.2 KB
    __shared__ float Wks[KC][DIM];     // 16 KB
    __shared__ float Wqs[KC][DIM];     // 16 KB  (total 41.2 KB)
    const int t = threadIdx.x;
    const int row0 = blockIdx.x * BM;
    const int tc = t & 15;
    const int tr = t >> 4;

    float acck[4][8], accq[4][8];
#pragma unroll
    for (int i = 0; i < 4; ++i)
#pragma unroll
        for (int j = 0; j < 8; ++j) { acck[i][j] = 0.f; accq[i][j] = 0.f; }

    for (int k0 = 0; k0 < DIM; k0 += KC) {
        {
            const int r = t >> 2;
            const int c = (t & 3) << 3;
            const int grow = row0 + r;
            float4 v0 = make_float4(0.f, 0.f, 0.f, 0.f), v1 = v0;
            if (grow < M) {
                const float* p = A + (size_t)grow * DIM + k0 + c;
                v0 = *(const float4*)p;
                v1 = *(const float4*)(p + 4);
            }
            *(float4*)&As[r][c] = v0;
            *(float4*)&As[r][c + 4] = v1;
        }
        {
            const float4* gk = (const float4*)(Wkw + (size_t)k0 * DIM);
            const float4* gq = (const float4*)(Wqw + (size_t)k0 * DIM);
            float4* sk = (float4*)&Wks[0][0];
            float4* sq = (float4*)&Wqs[0][0];
#pragma unroll
            for (int i = 0; i < 4; ++i) {
                sk[i * 256 + t] = gk[i * 256 + t];
                sq[i * 256 + t] = gq[i * 256 + t];
            }
        }
        __syncthreads();
#pragma unroll
        for (int kk = 0; kk < KC; kk += 4) {
            float4 a[4];
#pragma unroll
            for (int r = 0; r < 4; ++r)
                a[r] = *(const float4*)&As[tr * 4 + r][kk];
            float4 bk4[4][2], bq4[4][2];
#pragma unroll
            for (int k = 0; k < 4; ++k) {
                bk4[k][0] = *(const float4*)&Wks[kk + k][tc * 4];
                bk4[k][1] = *(const float4*)&Wks[kk + k][64 + tc * 4];
                bq4[k][0] = *(const float4*)&Wqs[kk + k][tc * 4];
                bq4[k][1] = *(const float4*)&Wqs[kk + k][64 + tc * 4];
            }
#pragma unroll
            for (int r = 0; r < 4; ++r) {
                const float ar[4] = {a[r].x, a[r].y, a[r].z, a[r].w};
#pragma unroll
                for (int k = 0; k < 4; ++k) {
                    acck[r][0] += ar[k] * bk4[k][0].x;
                    acck[r][1] += ar[k] * bk4[k][0].y;
                    acck[r][2] += ar[k] * bk4[k][0].z;
                    acck[r][3] += ar[k] * bk4[k][0].w;
                    acck[r][4] += ar[k] * bk4[k][1].x;
                    acck[r][5] += ar[k] * bk4[k][1].y;
                    acck[r][6] += ar[k] * bk4[k][1].z;
                    acck[r][7] += ar[k] * bk4[k][1].w;
                    accq[r][0] += ar[k] * bq4[k][0].x;
                    accq[r][1] += ar[k] * bq4[k][0].y;
                    accq[r][2] += ar[k] * bq4[k][0].z;
                    accq[r][3] += ar[k] * bq4[k][0].w;
                    accq[r][4] += ar[k] * bq4[k][1].x;
                    accq[r][5] += ar[k] * bq4[k][1].y;
                    accq[r][6] += ar[k] * bq4[k][1].z;
                    accq[r][7] += ar[k] * bq4[k][1].w;
                }
            }
        }
        __syncthreads();
    }
    const int c0 = tc * 4;
    float bks[8], bqs[8];
#pragma unroll
    for (int j = 0; j < 4; ++j) {
        bks[j] = bkw[c0 + j];
        bks[j + 4] = bkw[64 + c0 + j];
        bqs[j] = bqw[c0 + j];
        bqs[j + 4] = bqw[64 + c0 + j];
    }
#pragma unroll
    for (int r = 0; r < 4; ++r) {
        const int grow = row0 + tr * 4 + r;
        if (grow < M) {
            float* kp = K + (size_t)grow * DIM;
            float* qp = Q + (size_t)grow * DIM;
            *(float4*)(kp + c0) = make_float4(acck[r][0] + bks[0], acck[r][1] + bks[1],
                                              acck[r][2] + bks[2], acck[r][3] + bks[3]);
            *(float4*)(kp + 64 + c0) = make_float4(acck[r][4] + bks[4], acck[r][5] + bks[5],
                                                   acck[r][6] + bks[6], acck[r][7] + bks[7]);
            *(float4*)(qp + c0) = make_float4(accq[r][0] + bqs[0], accq[r][1] + bqs[1],
                                              accq[r][2] + bqs[2], accq[r][3] + bqs[3]);
            *(float4*)(qp + 64 + c0) = make_float4(accq[r][4] + bqs[4], accq[r][5] + bqs[5],
                                                   accq[r][6] + bqs[6], accq[r][7] + bqs[7]);
        }
    }
}

// ---------------- output projection: out[n] = dot(h[n,:], Wout) + bout ----------------
__global__ __launch_bounds__(256)
void out_kernel(const float* __restrict__ h, const float* __restrict__ Wout,
                const float* __restrict__ bout, float* __restrict__ out) {
    int tid = blockIdx.x * blockDim.x + threadIdx.x;
    int n = tid >> 5;
    if (n >= NN) return;
    int lane = tid & 31;
    const float4 h4 = *(const float4*)(h + (size_t)n * DIM + lane * 4);
    const float4 w4 = *(const float4*)(Wout + lane * 4);
    float s = h4.x * w4.x + h4.y * w4.y + h4.z * w4.z + h4.w * w4.w;
#pragma unroll
    for (int off = 16; off > 0; off >>= 1) s += __shfl_down(s, off, 32);
    if (lane == 0) out[n] = s + bout[0];
}

extern "C" void kernel_launch(void* const* d_in, const int* in_sizes, int n_in,
                              void* d_out, int out_size, void* d_ws, size_t ws_size,
                              hipStream_t stream) {
    const float* feats = (const float*)d_in[0];
    const int* esrc = (const int*)d_in[1];
    const int* edst = (const int*)d_in[2];
    const float* Win = (const float*)d_in[3];
    const float* bin_ = (const float*)d_in[4];
    const float* Wk = (const float*)d_in[5];
    const float* bk = (const float*)d_in[6];
    const float* Wq = (const float*)d_in[7];
    const float* bq = (const float*)d_in[8];
    const float* Wv = (const float*)d_in[9];
    const float* bv = (const float*)d_in[10];
    const float* Wl = (const float*)d_in[11];
    const float* bl = (const float*)d_in[12];
    const float* Wout = (const float*)d_in[13];
    const float* bout = (const float*)d_in[14];

    float* ws = (float*)d_ws;
    const size_t ND = (size_t)NN * DIM;
    float* h0 = ws;            // [N,D]
    float* h1 = ws + ND;       // [N,D]
    float* key = ws + 2 * ND;  // [N,D]  (reused for t = gelu(conv))
    float* qry = ws + 3 * ND;  // [N,D]  (agg aliases this — see agg_kernel)
    float* invdeg = ws + 4 * ND;                  // [N] float
    int* deg = (int*)(ws + 4 * ND + NN);          // [N]
    int* rowptr = deg + NN;                       // [N+1]
    int* cursor = rowptr + NN + 1;                // [N]
    int* ebuf = cursor + NN;                      // [E] src ids bucketed by dst

    dim3 b256(256);
    const int GB = (NN + 63) / 64;

    // ---- CSR build (once per launch) ----
    hipMemsetAsync(deg, 0, NN * sizeof(int), stream);
    deg_kernel<<<(EE + 255) / 256, b256, 0, stream>>>(edst, deg);
    scan_kernel<<<1, 1024, 0, stream>>>(deg, rowptr, cursor, invdeg);
    bucket_kernel<<<(EE + 255) / 256, b256, 0, stream>>>(esrc, edst, cursor, ebuf);

    // h = gelu(feats @ Win + bin)
    gemm128<EPI_GELU><<<GB, b256, 0, stream>>>(feats, Win, bin_, nullptr, h0, NN);

    const float* hin = h0;
    float* hout = h1;
    for (int i = 0; i < LL; ++i) {
        const float* Wki = Wk + (size_t)i * DIM * DIM;
        const float* Wqi = Wq + (size_t)i * DIM * DIM;
        const float* Wvi = Wv + (size_t)i * DIM * DIM;
        const float* Wli = Wl + (size_t)i * DIM * DIM;
        const float* bki = bk + (size_t)i * DIM;
        const float* bqi = bq + (size_t)i * DIM;
        const float* bvi = bv + (size_t)i * DIM;
        const float* bli = bl + (size_t)i * DIM;

        // key = h@Wk+bk, qry = h@Wq+bq (one A staging)
        gemm128_kq<<<GB, b256, 0, stream>>>(hin, Wki, bki, Wqi, bqi, key, qry, NN);
        // agg (in place over qry): mean_{e:dst=n} gelu(key[src]+qry[n]), * invdeg
        agg_kernel<<<(NN * 64) / 256, b256, 0, stream>>>(key, qry, rowptr, ebuf,
                                                         invdeg, qry);
        // t = gelu(agg @ Wv + bv) -> key buffer
        gemm128<EPI_GELU><<<GB, b256, 0, stream>>>(qry, Wvi, bvi, nullptr, key, NN);
        // h = t @ Wl + bl + resid
        gemm128<EPI_RESID><<<GB, b256, 0, stream>>>(key, Wli, bli, hin, hout, NN);
        float* tmp = (float*)hin;
        hin = hout;
        hout = tmp;
    }
    out_kernel<<<(NN * 32 + 255) / 256, b256, 0, stream>>>(hin, Wout, bout,
                                                           (float*)d_out);
}

// Round 8
// 739.806 us; speedup vs baseline: 1.2371x; 1.2371x over previous
//
#include <hip/hip_runtime.h>
#include <hip/hip_bf16.h>
#include <math.h>

#define NN 50000
#define EE 600000
#define DIM 128
#define LL 3
#define SCB 256
#define NBLK ((NN + SCB - 1) / SCB)   // 196

typedef float f32x16 __attribute__((ext_vector_type(16)));
typedef short bfrag __attribute__((ext_vector_type(8)));   // 8 bf16 (4 VGPRs)

__device__ __forceinline__ float gelu_f(float x) {
    return 0.5f * x * (1.0f + erff(x * 0.70710678118654752440f));
}

__device__ __forceinline__ ushort f2bf(float x) {
    union { float f; uint u; } v; v.f = x;
    uint r = v.u + 0x7fffu + ((v.u >> 16) & 1u);  // RTN-even
    return (ushort)(r >> 16);
}
__device__ __forceinline__ float bf2f(ushort h) {
    union { uint u; float f; } v; v.u = ((uint)h) << 16;
    return v.f;
}

// ---------------- CSR build ----------------
__global__ __launch_bounds__(256) void deg_kernel(const int* __restrict__ dst,
                                                  int* __restrict__ deg) {
    int e = blockIdx.x * blockDim.x + threadIdx.x;
    if (e < EE) atomicAdd(&deg[dst[e]], 1);
}

__global__ __launch_bounds__(256)
void partial_kernel(const int* __restrict__ deg, int* __restrict__ partial) {
    __shared__ int s[256];
    const int t = threadIdx.x;
    const int n = blockIdx.x * SCB + t;
    s[t] = (n < NN) ? deg[n] : 0;
    __syncthreads();
#pragma unroll
    for (int off = 128; off > 0; off >>= 1) {
        if (t < off) s[t] += s[t + off];
        __syncthreads();
    }
    if (t == 0) partial[blockIdx.x] = s[0];
}

__global__ __launch_bounds__(256)
void scanpart_kernel(const int* __restrict__ partial, int* __restrict__ pofs) {
    __shared__ int s[256];
    const int t = threadIdx.x;
    const int own = (t < NBLK) ? partial[t] : 0;
    s[t] = own;
    __syncthreads();
#pragma unroll
    for (int off = 1; off < 256; off <<= 1) {
        int v = s[t];
        int a = (t >= off) ? s[t - off] : 0;
        __syncthreads();
        s[t] = v + a;
        __syncthreads();
    }
    if (t < NBLK) pofs[t] = s[t] - own;  // exclusive
}

__global__ __launch_bounds__(256)
void fill_kernel(const int* __restrict__ deg, const int* __restrict__ pofs,
                 int* __restrict__ rowptr, int* __restrict__ cursor,
                 float* __restrict__ invdeg) {
    __shared__ int s[256];
    const int t = threadIdx.x;
    const int n = blockIdx.x * SCB + t;
    const int d = (n < NN) ? deg[n] : 0;
    s[t] = d;
    __syncthreads();
#pragma unroll
    for (int off = 1; off < 256; off <<= 1) {
        int v = s[t];
        int a = (t >= off) ? s[t - off] : 0;
        __syncthreads();
        s[t] = v + a;
        __syncthreads();
    }
    const int base = pofs[blockIdx.x] + s[t] - d;  // exclusive prefix
    if (n < NN) {
        rowptr[n] = base;
        cursor[n] = base;
        invdeg[n] = 1.0f / (float)(d < 1 ? 1 : d);
        if (n == NN - 1) rowptr[NN] = base + d;  // == EE
    }
}

__global__ __launch_bounds__(256)
void bucket_kernel(const int* __restrict__ src, const int* __restrict__ dst,
                   int* __restrict__ cursor, int* __restrict__ ebuf) {
    int e = blockIdx.x * blockDim.x + threadIdx.x;
    if (e < EE) {
        int slot = atomicAdd(&cursor[dst[e]], 1);
        ebuf[slot] = src[e];
    }
}

// ---------------- CSR gather aggregation ----------------
__global__ __launch_bounds__(256)
void agg_kernel(const float* __restrict__ key, const float* __restrict__ qry,
                const int* __restrict__ rowptr, const int* __restrict__ ebuf,
                const float* __restrict__ invdeg, float* __restrict__ agg) {
    int tid = blockIdx.x * blockDim.x + threadIdx.x;
    int n = tid >> 6;
    if (n >= NN) return;
    int c = (tid & 63) << 1;
    const float2 q2 = *(const float2*)(qry + (size_t)n * DIM + c);
    float ax = 0.f, ay = 0.f;
    const int lo = rowptr[n], hi = rowptr[n + 1];
    for (int j = lo; j < hi; ++j) {
        const int s = ebuf[j];
        const float2 k2 = *(const float2*)(key + (size_t)s * DIM + c);
        ax += gelu_f(k2.x + q2.x);
        ay += gelu_f(k2.y + q2.y);
    }
    const float inv = invdeg[n];
    *(float2*)(agg + (size_t)n * DIM + c) = make_float2(ax * inv, ay * inv);
}

// ---------------- MFMA GEMM: C[M,128] = epi(A[M,128] @ W[128,128] + bias) ------
// bf16 hi/lo split, 3-term MFMA (ah*bh + ah*bl + al*bh). BM=64, 4 waves,
// wave tile 32x64 (2 col-frags of 32x32), K chunked at 64.
// LDS layout: pre-swizzled fragment slots (lane-linear 16B) -> conflict-free reads.
enum { EPI_NONE = 0, EPI_GELU = 1, EPI_RESID = 2 };

template <int EPI>
__global__ __launch_bounds__(256)
void gemm_mfma(const float* __restrict__ A, const float* __restrict__ W,
               const float* __restrict__ bias, const float* __restrict__ resid,
               float* __restrict__ C, int M) {
    // A frag slots: [ks(4)][rblk(2)][lane(64)] ; W frag slots: [ks(4)][cf(4)][lane(64)]
    __shared__ ushort Ah[512 * 8], Al[512 * 8];    // 8 KB each
    __shared__ ushort Wh[1024 * 8], Wl[1024 * 8];  // 16 KB each  (total 48 KB)

    const int t = threadIdx.x;
    const int row0 = blockIdx.x * 64;
    const int w = t >> 6, l = t & 63;
    const int rblk = w & 1, ch = w >> 1;  // wave: rows rblk*32.., cols ch*64..

    f32x16 acc0 = {0.f}, acc1 = {0.f};
#pragma unroll
    for (int i = 0; i < 16; ++i) { acc0[i] = 0.f; acc1[i] = 0.f; }

    for (int c = 0; c < 2; ++c) {
        const int kc0 = c * 64;
        // ---- stage A chunk: thread t -> row=t>>2, ks=t&3 (16 consecutive k) ----
        {
            const int row = t >> 2, ks = t & 3;
            const int grow = row0 + row;
            float f[16];
            if (grow < M) {
                const float* p = A + (size_t)grow * DIM + kc0 + ks * 16;
                float4 q0 = *(const float4*)(p + 0);
                float4 q1 = *(const float4*)(p + 4);
                float4 q2 = *(const float4*)(p + 8);
                float4 q3 = *(const float4*)(p + 12);
                f[0]=q0.x; f[1]=q0.y; f[2]=q0.z; f[3]=q0.w;
                f[4]=q1.x; f[5]=q1.y; f[6]=q1.z; f[7]=q1.w;
                f[8]=q2.x; f[9]=q2.y; f[10]=q2.z; f[11]=q2.w;
                f[12]=q3.x; f[13]=q3.y; f[14]=q3.z; f[15]=q3.w;
            } else {
#pragma unroll
                for (int i = 0; i < 16; ++i) f[i] = 0.f;
            }
#pragma unroll
            for (int h = 0; h < 2; ++h) {
                bfrag hv, lv;
#pragma unroll
                for (int j = 0; j < 8; ++j) {
                    float x = f[h * 8 + j];
                    ushort hb = f2bf(x);
                    float r = x - bf2f(hb);
                    hv[j] = (short)hb;
                    lv[j] = (short)f2bf(r);
                }
                const int slot = (ks * 2 + (row >> 5)) * 64 + (row & 31) + 32 * h;
                *(bfrag*)&Ah[slot * 8] = hv;
                *(bfrag*)&Al[slot * 8] = lv;
            }
        }
        // ---- stage W chunk transposed: thread t -> n=t&127, k-half=t>>7 ----
        {
            const int n = t & 127, kh = t >> 7;
            const int cf = n >> 5;
#pragma unroll
            for (int g = 0; g < 4; ++g) {
                const int kl0 = kh * 32 + g * 8;
                bfrag hv, lv;
#pragma unroll
                for (int j = 0; j < 8; ++j) {
                    float x = W[(size_t)(kc0 + kl0 + j) * DIM + n];
                    ushort hb = f2bf(x);
                    float r = x - bf2f(hb);
                    hv[j] = (short)hb;
                    lv[j] = (short)f2bf(r);
                }
                const int ks = kl0 >> 4, half = (kl0 >> 3) & 1;
                const int slot = (ks * 4 + cf) * 64 + (n & 31) + 32 * half;
                *(bfrag*)&Wh[slot * 8] = hv;
                *(bfrag*)&Wl[slot * 8] = lv;
            }
        }
        __syncthreads();
        // ---- MFMA inner loop ----
#pragma unroll
        for (int ks = 0; ks < 4; ++ks) {
            const bfrag ah = *(const bfrag*)&Ah[((ks * 2 + rblk) * 64 + l) * 8];
            const bfrag al = *(const bfrag*)&Al[((ks * 2 + rblk) * 64 + l) * 8];
            {
                const int cf = ch * 2 + 0;
                const bfrag bh = *(const bfrag*)&Wh[((ks * 4 + cf) * 64 + l) * 8];
                const bfrag bl = *(const bfrag*)&Wl[((ks * 4 + cf) * 64 + l) * 8];
                acc0 = __builtin_amdgcn_mfma_f32_32x32x16_bf16(al, bh, acc0, 0, 0, 0);
                acc0 = __builtin_amdgcn_mfma_f32_32x32x16_bf16(ah, bl, acc0, 0, 0, 0);
                acc0 = __builtin_amdgcn_mfma_f32_32x32x16_bf16(ah, bh, acc0, 0, 0, 0);
            }
            {
                const int cf = ch * 2 + 1;
                const bfrag bh = *(const bfrag*)&Wh[((ks * 4 + cf) * 64 + l) * 8];
                const bfrag bl = *(const bfrag*)&Wl[((ks * 4 + cf) * 64 + l) * 8];
                acc1 = __builtin_amdgcn_mfma_f32_32x32x16_bf16(al, bh, acc1, 0, 0, 0);
                acc1 = __builtin_amdgcn_mfma_f32_32x32x16_bf16(ah, bl, acc1, 0, 0, 0);
                acc1 = __builtin_amdgcn_mfma_f32_32x32x16_bf16(ah, bh, acc1, 0, 0, 0);
            }
        }
        __syncthreads();
    }
    // ---- epilogue: C/D map col=lane&31, row=(reg&3)+8*(reg>>2)+4*(lane>>5) ----
    const int colbase = ch * 64 + (l & 31);
    const int rbase = row0 + rblk * 32 + 4 * (l >> 5);
#pragma unroll
    for (int cf2 = 0; cf2 < 2; ++cf2) {
        const int col = colbase + cf2 * 32;
        const float bv = bias[col];
#pragma unroll
        for (int r = 0; r < 16; ++r) {
            const int grow = rbase + (r & 3) + 8 * (r >> 2);
            if (grow < M) {
                float o = (cf2 == 0 ? acc0[r] : acc1[r]) + bv;
                if (EPI == EPI_GELU) o = gelu_f(o);
                if (EPI == EPI_RESID) o += resid[(size_t)grow * DIM + col];
                C[(size_t)grow * DIM + col] = o;
            }
        }
    }
}

// ---------------- output projection ----------------
__global__ __launch_bounds__(256)
void out_kernel(const float* __restrict__ h, const float* __restrict__ Wout,
                const float* __restrict__ bout, float* __restrict__ out) {
    int tid = blockIdx.x * blockDim.x + threadIdx.x;
    int n = tid >> 5;
    if (n >= NN) return;
    int lane = tid & 31;
    const float4 h4 = *(const float4*)(h + (size_t)n * DIM + lane * 4);
    const float4 w4 = *(const float4*)(Wout + lane * 4);
    float s = h4.x * w4.x + h4.y * w4.y + h4.z * w4.z + h4.w * w4.w;
#pragma unroll
    for (int off = 16; off > 0; off >>= 1) s += __shfl_down(s, off, 32);
    if (lane == 0) out[n] = s + bout[0];
}

extern "C" void kernel_launch(void* const* d_in, const int* in_sizes, int n_in,
                              void* d_out, int out_size, void* d_ws, size_t ws_size,
                              hipStream_t stream) {
    const float* feats = (const float*)d_in[0];
    const int* esrc = (const int*)d_in[1];
    const int* edst = (const int*)d_in[2];
    const float* Win = (const float*)d_in[3];
    const float* bin_ = (const float*)d_in[4];
    const float* Wk = (const float*)d_in[5];
    const float* bk = (const float*)d_in[6];
    const float* Wq = (const float*)d_in[7];
    const float* bq = (const float*)d_in[8];
    const float* Wv = (const float*)d_in[9];
    const float* bv = (const float*)d_in[10];
    const float* Wl = (const float*)d_in[11];
    const float* bl = (const float*)d_in[12];
    const float* Wout = (const float*)d_in[13];
    const float* bout = (const float*)d_in[14];

    float* ws = (float*)d_ws;
    const size_t ND = (size_t)NN * DIM;
    float* h0 = ws;            // [N,D]
    float* h1 = ws + ND;       // [N,D]
    float* key = ws + 2 * ND;  // [N,D]
    float* qry = ws + 3 * ND;  // [N,D]  (agg aliases this)
    float* invdeg = ws + 4 * ND;                  // [N]
    int* deg = (int*)(ws + 4 * ND + NN);          // [N]
    int* rowptr = deg + NN;                       // [N+1]
    int* cursor = rowptr + NN + 1;                // [N]
    int* ebuf = cursor + NN;                      // [E]
    int* partial = ebuf + EE;                     // [NBLK]
    int* pofs = partial + NBLK;                   // [NBLK]

    dim3 b256(256);
    const int GB = (NN + 63) / 64;  // 782 MFMA-GEMM blocks

    // ---- CSR build ----
    hipMemsetAsync(deg, 0, NN * sizeof(int), stream);
    deg_kernel<<<(EE + 255) / 256, b256, 0, stream>>>(edst, deg);
    partial_kernel<<<NBLK, b256, 0, stream>>>(deg, partial);
    scanpart_kernel<<<1, b256, 0, stream>>>(partial, pofs);
    fill_kernel<<<NBLK, b256, 0, stream>>>(deg, pofs, rowptr, cursor, invdeg);
    bucket_kernel<<<(EE + 255) / 256, b256, 0, stream>>>(esrc, edst, cursor, ebuf);

    // h = gelu(feats @ Win + bin)
    gemm_mfma<EPI_GELU><<<GB, b256, 0, stream>>>(feats, Win, bin_, nullptr, h0, NN);

    const float* hin = h0;
    float* hout = h1;
    for (int i = 0; i < LL; ++i) {
        const float* Wki = Wk + (size_t)i * DIM * DIM;
        const float* Wqi = Wq + (size_t)i * DIM * DIM;
        const float* Wvi = Wv + (size_t)i * DIM * DIM;
        const float* Wli = Wl + (size_t)i * DIM * DIM;
        const float* bki = bk + (size_t)i * DIM;
        const float* bqi = bq + (size_t)i * DIM;
        const float* bvi = bv + (size_t)i * DIM;
        const float* bli = bl + (size_t)i * DIM;

        gemm_mfma<EPI_NONE><<<GB, b256, 0, stream>>>(hin, Wki, bki, nullptr, key, NN);
        gemm_mfma<EPI_NONE><<<GB, b256, 0, stream>>>(hin, Wqi, bqi, nullptr, qry, NN);
        agg_kernel<<<(NN * 64) / 256, b256, 0, stream>>>(key, qry, rowptr, ebuf,
                                                         invdeg, qry);
        gemm_mfma<EPI_GELU><<<GB, b256, 0, stream>>>(qry, Wvi, bvi, nullptr, key, NN);
        gemm_mfma<EPI_RESID><<<GB, b256, 0, stream>>>(key, Wli, bli, hin, hout, NN);
        float* tmp = (float*)hin;
        hin = hout;
        hout = tmp;
    }
    out_kernel<<<(NN * 32 + 255) / 256, b256, 0, stream>>>(hin, Wout, bout,
                                                           (float*)d_out);
}

// Round 9
// 630.313 us; speedup vs baseline: 1.4519x; 1.1737x over previous
//
#include <hip/hip_runtime.h>
#include <hip/hip_bf16.h>
#include <math.h>

#define NN 50000
#define EE 600000
#define DIM 128
#define LL 3
#define SCB 256
#define NBLK ((NN + SCB - 1) / SCB)   // 196

typedef float f32x16 __attribute__((ext_vector_type(16)));
typedef short bfrag __attribute__((ext_vector_type(8)));   // 8 bf16 (4 VGPRs)

__device__ __forceinline__ float gelu_f(float x) {
    return 0.5f * x * (1.0f + erff(x * 0.70710678118654752440f));
}

__device__ __forceinline__ ushort f2bf(float x) {
    union { float f; uint u; } v; v.f = x;
    uint r = v.u + 0x7fffu + ((v.u >> 16) & 1u);  // RTN-even
    return (ushort)(r >> 16);
}
__device__ __forceinline__ float bf2f(ushort h) {
    union { uint u; float f; } v; v.u = ((uint)h) << 16;
    return v.f;
}

// ---------------- CSR build ----------------
__global__ __launch_bounds__(256) void deg_kernel(const int* __restrict__ dst,
                                                  int* __restrict__ deg) {
    int e = blockIdx.x * blockDim.x + threadIdx.x;
    if (e < EE) atomicAdd(&deg[dst[e]], 1);
}

__global__ __launch_bounds__(256)
void partial_kernel(const int* __restrict__ deg, int* __restrict__ partial) {
    __shared__ int s[256];
    const int t = threadIdx.x;
    const int n = blockIdx.x * SCB + t;
    s[t] = (n < NN) ? deg[n] : 0;
    __syncthreads();
#pragma unroll
    for (int off = 128; off > 0; off >>= 1) {
        if (t < off) s[t] += s[t + off];
        __syncthreads();
    }
    if (t == 0) partial[blockIdx.x] = s[0];
}

__global__ __launch_bounds__(256)
void scanpart_kernel(const int* __restrict__ partial, int* __restrict__ pofs) {
    __shared__ int s[256];
    const int t = threadIdx.x;
    const int own = (t < NBLK) ? partial[t] : 0;
    s[t] = own;
    __syncthreads();
#pragma unroll
    for (int off = 1; off < 256; off <<= 1) {
        int v = s[t];
        int a = (t >= off) ? s[t - off] : 0;
        __syncthreads();
        s[t] = v + a;
        __syncthreads();
    }
    if (t < NBLK) pofs[t] = s[t] - own;  // exclusive
}

__global__ __launch_bounds__(256)
void fill_kernel(const int* __restrict__ deg, const int* __restrict__ pofs,
                 int* __restrict__ rowptr, int* __restrict__ cursor,
                 float* __restrict__ invdeg) {
    __shared__ int s[256];
    const int t = threadIdx.x;
    const int n = blockIdx.x * SCB + t;
    const int d = (n < NN) ? deg[n] : 0;
    s[t] = d;
    __syncthreads();
#pragma unroll
    for (int off = 1; off < 256; off <<= 1) {
        int v = s[t];
        int a = (t >= off) ? s[t - off] : 0;
        __syncthreads();
        s[t] = v + a;
        __syncthreads();
    }
    const int base = pofs[blockIdx.x] + s[t] - d;  // exclusive prefix
    if (n < NN) {
        rowptr[n] = base;
        cursor[n] = base;
        invdeg[n] = 1.0f / (float)(d < 1 ? 1 : d);
        if (n == NN - 1) rowptr[NN] = base + d;  // == EE
    }
}

__global__ __launch_bounds__(256)
void bucket_kernel(const int* __restrict__ src, const int* __restrict__ dst,
                   int* __restrict__ cursor, int* __restrict__ ebuf) {
    int e = blockIdx.x * blockDim.x + threadIdx.x;
    if (e < EE) {
        int slot = atomicAdd(&cursor[dst[e]], 1);
        ebuf[slot] = src[e];
    }
}

// ---------------- weight pre-split: fp32 W -> bf16 hi/lo fragment slots --------
// Layout per matrix m: [chunk c(2)][hi/lo(2)][slot(1024)][8 ushorts]  (64 KB)
// Slot math mirrors gemm_mfma's staging exactly.
__global__ __launch_bounds__(256)
void wsplit_kernel(const float* __restrict__ Win, const float* __restrict__ Wk,
                   const float* __restrict__ Wq, const float* __restrict__ Wv,
                   const float* __restrict__ Wl, ushort* __restrict__ pre) {
    const int b = blockIdx.x;       // 26 blocks: (matrix m, chunk c)
    const int m = b >> 1, c = b & 1;
    const float* W;
    if (m == 0) W = Win;
    else if (m <= 3) W = Wk + (size_t)(m - 1) * DIM * DIM;
    else if (m <= 6) W = Wq + (size_t)(m - 4) * DIM * DIM;
    else if (m <= 9) W = Wv + (size_t)(m - 7) * DIM * DIM;
    else W = Wl + (size_t)(m - 10) * DIM * DIM;
    ushort* dst = pre + (size_t)m * (4 * 1024 * 8) + (size_t)c * (2 * 1024 * 8);

    const int t = threadIdx.x;
    const int kc0 = c * 64;
    const int n = t & 127, kh = t >> 7;
    const int cf = n >> 5;
#pragma unroll
    for (int g = 0; g < 4; ++g) {
        const int kl0 = kh * 32 + g * 8;
#pragma unroll
        for (int j = 0; j < 8; ++j) {
            float x = W[(size_t)(kc0 + kl0 + j) * DIM + n];
            ushort hb = f2bf(x);
            float r = x - bf2f(hb);
            const int ks = kl0 >> 4, half = (kl0 >> 3) & 1;
            const int slot = (ks * 4 + cf) * 64 + (n & 31) + 32 * half;
            dst[slot * 8 + j] = hb;                  // hi plane
            dst[1024 * 8 + slot * 8 + j] = f2bf(r);  // lo plane
        }
    }
}

// ---------------- CSR gather aggregation (4-wide MLP) ----------------
__global__ __launch_bounds__(256)
void agg_kernel(const float* __restrict__ key, const float* __restrict__ qry,
                const int* __restrict__ rowptr, const int* __restrict__ ebuf,
                const float* __restrict__ invdeg, float* __restrict__ agg) {
    int tid = blockIdx.x * blockDim.x + threadIdx.x;
    int n = tid >> 6;
    if (n >= NN) return;
    int c = (tid & 63) << 1;
    const float2 q2 = *(const float2*)(qry + (size_t)n * DIM + c);
    float ax = 0.f, ay = 0.f;
    int j = rowptr[n];
    const int hi = rowptr[n + 1];
    for (; j + 4 <= hi; j += 4) {
        const int s0 = ebuf[j], s1 = ebuf[j + 1], s2 = ebuf[j + 2], s3 = ebuf[j + 3];
        const float2 k0 = *(const float2*)(key + (size_t)s0 * DIM + c);
        const float2 k1 = *(const float2*)(key + (size_t)s1 * DIM + c);
        const float2 k2 = *(const float2*)(key + (size_t)s2 * DIM + c);
        const float2 k3 = *(const float2*)(key + (size_t)s3 * DIM + c);
        ax += gelu_f(k0.x + q2.x); ay += gelu_f(k0.y + q2.y);
        ax += gelu_f(k1.x + q2.x); ay += gelu_f(k1.y + q2.y);
        ax += gelu_f(k2.x + q2.x); ay += gelu_f(k2.y + q2.y);
        ax += gelu_f(k3.x + q2.x); ay += gelu_f(k3.y + q2.y);
    }
    for (; j < hi; ++j) {
        const int s = ebuf[j];
        const float2 k2 = *(const float2*)(key + (size_t)s * DIM + c);
        ax += gelu_f(k2.x + q2.x);
        ay += gelu_f(k2.y + q2.y);
    }
    const float inv = invdeg[n];
    *(float2*)(agg + (size_t)n * DIM + c) = make_float2(ax * inv, ay * inv);
}

// ---------------- MFMA GEMM: C[M,128] = epi(A[M,128] @ W[128,128] + bias) ------
// bf16 hi/lo split, 3-term MFMA. W comes PRE-SPLIT in fragment-slot layout.
enum { EPI_NONE = 0, EPI_GELU = 1, EPI_RESID = 2 };

template <int EPI>
__global__ __launch_bounds__(256)
void gemm_mfma(const float* __restrict__ A, const ushort* __restrict__ wpre,
               const float* __restrict__ bias, const float* __restrict__ resid,
               float* __restrict__ C, int M) {
    __shared__ ushort Ah[512 * 8], Al[512 * 8];    // 8 KB each
    __shared__ ushort Wh[1024 * 8], Wl[1024 * 8];  // 16 KB each  (total 48 KB)

    const int t = threadIdx.x;
    const int row0 = blockIdx.x * 64;
    const int w = t >> 6, l = t & 63;
    const int rblk = w & 1, ch = w >> 1;  // wave: rows rblk*32.., cols ch*64..

    f32x16 acc0, acc1;
#pragma unroll
    for (int i = 0; i < 16; ++i) { acc0[i] = 0.f; acc1[i] = 0.f; }

    for (int c = 0; c < 2; ++c) {
        const int kc0 = c * 64;
        // ---- stage A chunk: thread t -> row=t>>2, ks=t&3 (16 consecutive k) ----
        {
            const int row = t >> 2, ks = t & 3;
            const int grow = row0 + row;
            float f[16];
            if (grow < M) {
                const float* p = A + (size_t)grow * DIM + kc0 + ks * 16;
                float4 q0 = *(const float4*)(p + 0);
                float4 q1 = *(const float4*)(p + 4);
                float4 q2 = *(const float4*)(p + 8);
                float4 q3 = *(const float4*)(p + 12);
                f[0]=q0.x; f[1]=q0.y; f[2]=q0.z; f[3]=q0.w;
                f[4]=q1.x; f[5]=q1.y; f[6]=q1.z; f[7]=q1.w;
                f[8]=q2.x; f[9]=q2.y; f[10]=q2.z; f[11]=q2.w;
                f[12]=q3.x; f[13]=q3.y; f[14]=q3.z; f[15]=q3.w;
            } else {
#pragma unroll
                for (int i = 0; i < 16; ++i) f[i] = 0.f;
            }
#pragma unroll
            for (int h = 0; h < 2; ++h) {
                bfrag hv, lv;
#pragma unroll
                for (int j = 0; j < 8; ++j) {
                    float x = f[h * 8 + j];
                    ushort hb = f2bf(x);
                    float r = x - bf2f(hb);
                    hv[j] = (short)hb;
                    lv[j] = (short)f2bf(r);
                }
                const int slot = (ks * 2 + (row >> 5)) * 64 + (row & 31) + 32 * h;
                *(bfrag*)&Ah[slot * 8] = hv;
                *(bfrag*)&Al[slot * 8] = lv;
            }
        }
        // ---- stage W chunk: flat float4 copy of pre-split slots ----
        {
            const float4* gh = (const float4*)(wpre + ((size_t)c * 2 + 0) * 1024 * 8);
            const float4* gl = (const float4*)(wpre + ((size_t)c * 2 + 1) * 1024 * 8);
            float4* sh = (float4*)&Wh[0];
            float4* sl = (float4*)&Wl[0];
#pragma unroll
            for (int i = 0; i < 4; ++i) {
                sh[i * 256 + t] = gh[i * 256 + t];
                sl[i * 256 + t] = gl[i * 256 + t];
            }
        }
        __syncthreads();
        // ---- MFMA inner loop ----
#pragma unroll
        for (int ks = 0; ks < 4; ++ks) {
            const bfrag ah = *(const bfrag*)&Ah[((ks * 2 + rblk) * 64 + l) * 8];
            const bfrag al = *(const bfrag*)&Al[((ks * 2 + rblk) * 64 + l) * 8];
            {
                const int cf = ch * 2 + 0;
                const bfrag bh = *(const bfrag*)&Wh[((ks * 4 + cf) * 64 + l) * 8];
                const bfrag bl = *(const bfrag*)&Wl[((ks * 4 + cf) * 64 + l) * 8];
                acc0 = __builtin_amdgcn_mfma_f32_32x32x16_bf16(al, bh, acc0, 0, 0, 0);
                acc0 = __builtin_amdgcn_mfma_f32_32x32x16_bf16(ah, bl, acc0, 0, 0, 0);
                acc0 = __builtin_amdgcn_mfma_f32_32x32x16_bf16(ah, bh, acc0, 0, 0, 0);
            }
            {
                const int cf = ch * 2 + 1;
                const bfrag bh = *(const bfrag*)&Wh[((ks * 4 + cf) * 64 + l) * 8];
                const bfrag bl = *(const bfrag*)&Wl[((ks * 4 + cf) * 64 + l) * 8];
                acc1 = __builtin_amdgcn_mfma_f32_32x32x16_bf16(al, bh, acc1, 0, 0, 0);
                acc1 = __builtin_amdgcn_mfma_f32_32x32x16_bf16(ah, bl, acc1, 0, 0, 0);
                acc1 = __builtin_amdgcn_mfma_f32_32x32x16_bf16(ah, bh, acc1, 0, 0, 0);
            }
        }
        __syncthreads();
    }
    // ---- epilogue: C/D map col=lane&31, row=(reg&3)+8*(reg>>2)+4*(lane>>5) ----
    const int colbase = ch * 64 + (l & 31);
    const int rbase = row0 + rblk * 32 + 4 * (l >> 5);
#pragma unroll
    for (int cf2 = 0; cf2 < 2; ++cf2) {
        const int col = colbase + cf2 * 32;
        const float bv = bias[col];
#pragma unroll
        for (int r = 0; r < 16; ++r) {
            const int grow = rbase + (r & 3) + 8 * (r >> 2);
            if (grow < M) {
                float o = (cf2 == 0 ? acc0[r] : acc1[r]) + bv;
                if (EPI == EPI_GELU) o = gelu_f(o);
                if (EPI == EPI_RESID) o += resid[(size_t)grow * DIM + col];
                C[(size_t)grow * DIM + col] = o;
            }
        }
    }
}

// ---------------- output projection ----------------
__global__ __launch_bounds__(256)
void out_kernel(const float* __restrict__ h, const float* __restrict__ Wout,
                const float* __restrict__ bout, float* __restrict__ out) {
    int tid = blockIdx.x * blockDim.x + threadIdx.x;
    int n = tid >> 5;
    if (n >= NN) return;
    int lane = tid & 31;
    const float4 h4 = *(const float4*)(h + (size_t)n * DIM + lane * 4);
    const float4 w4 = *(const float4*)(Wout + lane * 4);
    float s = h4.x * w4.x + h4.y * w4.y + h4.z * w4.z + h4.w * w4.w;
#pragma unroll
    for (int off = 16; off > 0; off >>= 1) s += __shfl_down(s, off, 32);
    if (lane == 0) out[n] = s + bout[0];
}

extern "C" void kernel_launch(void* const* d_in, const int* in_sizes, int n_in,
                              void* d_out, int out_size, void* d_ws, size_t ws_size,
                              hipStream_t stream) {
    const float* feats = (const float*)d_in[0];
    const int* esrc = (const int*)d_in[1];
    const int* edst = (const int*)d_in[2];
    const float* Win = (const float*)d_in[3];
    const float* bin_ = (const float*)d_in[4];
    const float* Wk = (const float*)d_in[5];
    const float* bk = (const float*)d_in[6];
    const float* Wq = (const float*)d_in[7];
    const float* bq = (const float*)d_in[8];
    const float* Wv = (const float*)d_in[9];
    const float* bv = (const float*)d_in[10];
    const float* Wl = (const float*)d_in[11];
    const float* bl = (const float*)d_in[12];
    const float* Wout = (const float*)d_in[13];
    const float* bout = (const float*)d_in[14];

    float* ws = (float*)d_ws;
    const size_t ND = (size_t)NN * DIM;
    float* h0 = ws;            // [N,D]
    float* h1 = ws + ND;       // [N,D]
    float* key = ws + 2 * ND;  // [N,D]
    float* qry = ws + 3 * ND;  // [N,D]  (agg writes in place — race-free per row)
    float* invdeg = ws + 4 * ND;                  // [N]
    int* deg = (int*)(ws + 4 * ND + NN);          // [N]
    int* rowptr = deg + NN;                       // [N+1]
    int* cursor = rowptr + NN + 1;                // [N]
    int* ebuf = cursor + NN;                      // [E]
    int* partial = ebuf + EE;                     // [NBLK]
    int* pofs = partial + NBLK;                   // [NBLK]
    // 16B-aligned pre-split weight area: 13 matrices x 32768 ushorts (832 KB)
    size_t intofs = (size_t)((pofs + NBLK) - (int*)d_ws);
    intofs = (intofs + 3) & ~(size_t)3;
    ushort* pre = (ushort*)((int*)d_ws + intofs);

    dim3 b256(256);
    const int GB = (NN + 63) / 64;  // 782 MFMA-GEMM blocks
    const size_t WPM = 4 * 1024 * 8;  // ushorts per pre-split matrix

    // ---- weight pre-split (once per launch) ----
    wsplit_kernel<<<26, b256, 0, stream>>>(Win, Wk, Wq, Wv, Wl, pre);

    // ---- CSR build ----
    hipMemsetAsync(deg, 0, NN * sizeof(int), stream);
    deg_kernel<<<(EE + 255) / 256, b256, 0, stream>>>(edst, deg);
    partial_kernel<<<NBLK, b256, 0, stream>>>(deg, partial);
    scanpart_kernel<<<1, b256, 0, stream>>>(partial, pofs);
    fill_kernel<<<NBLK, b256, 0, stream>>>(deg, pofs, rowptr, cursor, invdeg);
    bucket_kernel<<<(EE + 255) / 256, b256, 0, stream>>>(esrc, edst, cursor, ebuf);

    // h = gelu(feats @ Win + bin)
    gemm_mfma<EPI_GELU><<<GB, b256, 0, stream>>>(feats, pre + 0 * WPM, bin_,
                                                 nullptr, h0, NN);

    const float* hin = h0;
    float* hout = h1;
    for (int i = 0; i < LL; ++i) {
        const ushort* wk = pre + (size_t)(1 + i) * WPM;
        const ushort* wq = pre + (size_t)(4 + i) * WPM;
        const ushort* wv = pre + (size_t)(7 + i) * WPM;
        const ushort* wl = pre + (size_t)(10 + i) * WPM;
        const float* bki = bk + (size_t)i * DIM;
        const float* bqi = bq + (size_t)i * DIM;
        const float* bvi = bv + (size_t)i * DIM;
        const float* bli = bl + (size_t)i * DIM;

        gemm_mfma<EPI_NONE><<<GB, b256, 0, stream>>>(hin, wk, bki, nullptr, key, NN);
        gemm_mfma<EPI_NONE><<<GB, b256, 0, stream>>>(hin, wq, bqi, nullptr, qry, NN);
        agg_kernel<<<(NN * 64) / 256, b256, 0, stream>>>(key, qry, rowptr, ebuf,
                                                         invdeg, qry);
        gemm_mfma<EPI_GELU><<<GB, b256, 0, stream>>>(qry, wv, bvi, nullptr, key, NN);
        gemm_mfma<EPI_RESID><<<GB, b256, 0, stream>>>(key, wl, bli, hin, hout, NN);
        float* tmp = (float*)hin;
        hin = hout;
        hout = tmp;
    }
    out_kernel<<<(NN * 32 + 255) / 256, b256, 0, stream>>>(hin, Wout, bout,
                                                           (float*)d_out);
}

// Round 10
// 537.112 us; speedup vs baseline: 1.7039x; 1.1735x over previous
//
#include <hip/hip_runtime.h>
#include <hip/hip_bf16.h>
#include <math.h>

#define NN 50000
#define EE 600000
#define DIM 128
#define LL 3
#define SCB 256
#define NBLK ((NN + SCB - 1) / SCB)   // 196
#define CTS 132                        // Ct row stride (floats)

typedef float f32x16 __attribute__((ext_vector_type(16)));
typedef short bfrag __attribute__((ext_vector_type(8)));   // 8 bf16 (4 VGPRs)

__device__ __forceinline__ float gelu_f(float x) {
    return 0.5f * x * (1.0f + erff(x * 0.70710678118654752440f));
}

__device__ __forceinline__ ushort f2bf(float x) {
    union { float f; uint u; } v; v.f = x;
    uint r = v.u + 0x7fffu + ((v.u >> 16) & 1u);  // RTN-even
    return (ushort)(r >> 16);
}
__device__ __forceinline__ float bf2f(ushort h) {
    union { uint u; float f; } v; v.u = ((uint)h) << 16;
    return v.f;
}

// ---------------- CSR build ----------------
__global__ __launch_bounds__(256) void deg_kernel(const int* __restrict__ dst,
                                                  int* __restrict__ deg) {
    int e = blockIdx.x * blockDim.x + threadIdx.x;
    if (e < EE) atomicAdd(&deg[dst[e]], 1);
}

__global__ __launch_bounds__(256)
void partial_kernel(const int* __restrict__ deg, int* __restrict__ partial) {
    __shared__ int s[256];
    const int t = threadIdx.x;
    const int n = blockIdx.x * SCB + t;
    s[t] = (n < NN) ? deg[n] : 0;
    __syncthreads();
#pragma unroll
    for (int off = 128; off > 0; off >>= 1) {
        if (t < off) s[t] += s[t + off];
        __syncthreads();
    }
    if (t == 0) partial[blockIdx.x] = s[0];
}

__global__ __launch_bounds__(256)
void scanpart_kernel(const int* __restrict__ partial, int* __restrict__ pofs) {
    __shared__ int s[256];
    const int t = threadIdx.x;
    const int own = (t < NBLK) ? partial[t] : 0;
    s[t] = own;
    __syncthreads();
#pragma unroll
    for (int off = 1; off < 256; off <<= 1) {
        int v = s[t];
        int a = (t >= off) ? s[t - off] : 0;
        __syncthreads();
        s[t] = v + a;
        __syncthreads();
    }
    if (t < NBLK) pofs[t] = s[t] - own;  // exclusive
}

__global__ __launch_bounds__(256)
void fill_kernel(const int* __restrict__ deg, const int* __restrict__ pofs,
                 int* __restrict__ rowptr, int* __restrict__ cursor,
                 float* __restrict__ invdeg) {
    __shared__ int s[256];
    const int t = threadIdx.x;
    const int n = blockIdx.x * SCB + t;
    const int d = (n < NN) ? deg[n] : 0;
    s[t] = d;
    __syncthreads();
#pragma unroll
    for (int off = 1; off < 256; off <<= 1) {
        int v = s[t];
        int a = (t >= off) ? s[t - off] : 0;
        __syncthreads();
        s[t] = v + a;
        __syncthreads();
    }
    const int base = pofs[blockIdx.x] + s[t] - d;  // exclusive prefix
    if (n < NN) {
        rowptr[n] = base;
        cursor[n] = base;
        invdeg[n] = 1.0f / (float)(d < 1 ? 1 : d);
        if (n == NN - 1) rowptr[NN] = base + d;  // == EE
    }
}

__global__ __launch_bounds__(256)
void bucket_kernel(const int* __restrict__ src, const int* __restrict__ dst,
                   int* __restrict__ cursor, int* __restrict__ ebuf) {
    int e = blockIdx.x * blockDim.x + threadIdx.x;
    if (e < EE) {
        int slot = atomicAdd(&cursor[dst[e]], 1);
        ebuf[slot] = src[e];
    }
}

// ---------------- weight pre-split: fp32 W -> bf16 hi/lo fragment slots --------
__global__ __launch_bounds__(256)
void wsplit_kernel(const float* __restrict__ Win, const float* __restrict__ Wk,
                   const float* __restrict__ Wq, const float* __restrict__ Wv,
                   const float* __restrict__ Wl, ushort* __restrict__ pre) {
    const int b = blockIdx.x;       // 26 blocks: (matrix m, chunk c)
    const int m = b >> 1, c = b & 1;
    const float* W;
    if (m == 0) W = Win;
    else if (m <= 3) W = Wk + (size_t)(m - 1) * DIM * DIM;
    else if (m <= 6) W = Wq + (size_t)(m - 4) * DIM * DIM;
    else if (m <= 9) W = Wv + (size_t)(m - 7) * DIM * DIM;
    else W = Wl + (size_t)(m - 10) * DIM * DIM;
    ushort* dst = pre + (size_t)m * (4 * 1024 * 8) + (size_t)c * (2 * 1024 * 8);

    const int t = threadIdx.x;
    const int kc0 = c * 64;
    const int n = t & 127, kh = t >> 7;
    const int cf = n >> 5;
#pragma unroll
    for (int g = 0; g < 4; ++g) {
        const int kl0 = kh * 32 + g * 8;
#pragma unroll
        for (int j = 0; j < 8; ++j) {
            float x = W[(size_t)(kc0 + kl0 + j) * DIM + n];
            ushort hb = f2bf(x);
            float r = x - bf2f(hb);
            const int ks = kl0 >> 4, half = (kl0 >> 3) & 1;
            const int slot = (ks * 4 + cf) * 64 + (n & 31) + 32 * half;
            dst[slot * 8 + j] = hb;                  // hi plane
            dst[1024 * 8 + slot * 8 + j] = f2bf(r);  // lo plane
        }
    }
}

// ---------------- CSR gather aggregation (8-wide load batching) ----------------
// Sequential accumulation order preserved (bitwise == scalar loop).
__global__ __launch_bounds__(256)
void agg_kernel(const float* __restrict__ key, const float* qry,
                const int* __restrict__ rowptr, const int* __restrict__ ebuf,
                const float* __restrict__ invdeg, float* agg) {
    int tid = blockIdx.x * blockDim.x + threadIdx.x;
    int n = tid >> 6;
    if (n >= NN) return;
    int c = (tid & 63) << 1;
    const float2 q2 = *(const float2*)(qry + (size_t)n * DIM + c);
    float ax = 0.f, ay = 0.f;
    int j = rowptr[n];
    const int hi = rowptr[n + 1];
    for (; j + 8 <= hi; j += 8) {
        float2 k[8];
#pragma unroll
        for (int u = 0; u < 8; ++u)
            k[u] = *(const float2*)(key + (size_t)ebuf[j + u] * DIM + c);
#pragma unroll
        for (int u = 0; u < 8; ++u) {
            ax += gelu_f(k[u].x + q2.x);
            ay += gelu_f(k[u].y + q2.y);
        }
    }
    for (; j < hi; ++j) {
        const float2 k2 = *(const float2*)(key + (size_t)ebuf[j] * DIM + c);
        ax += gelu_f(k2.x + q2.x);
        ay += gelu_f(k2.y + q2.y);
    }
    const float inv = invdeg[n];
    *(float2*)(agg + (size_t)n * DIM + c) = make_float2(ax * inv, ay * inv);
}

// ---------------- MFMA GEMM machinery ----------------
enum { EPI_NONE = 0, EPI_GELU = 1, EPI_RESID = 2 };

// Stage A chunk (64 rows x 64 k) as bf16 hi/lo fragment slots.
__device__ __forceinline__ void stage_A(const float* __restrict__ A, int M,
                                        int row0, int kc0, int t,
                                        ushort* Ah, ushort* Al) {
    const int row = t >> 2, ks = t & 3;
    const int grow = row0 + row;
    float f[16];
    if (grow < M) {
        const float* p = A + (size_t)grow * DIM + kc0 + ks * 16;
        float4 q0 = *(const float4*)(p + 0);
        float4 q1 = *(const float4*)(p + 4);
        float4 q2 = *(const float4*)(p + 8);
        float4 q3 = *(const float4*)(p + 12);
        f[0]=q0.x; f[1]=q0.y; f[2]=q0.z; f[3]=q0.w;
        f[4]=q1.x; f[5]=q1.y; f[6]=q1.z; f[7]=q1.w;
        f[8]=q2.x; f[9]=q2.y; f[10]=q2.z; f[11]=q2.w;
        f[12]=q3.x; f[13]=q3.y; f[14]=q3.z; f[15]=q3.w;
    } else {
#pragma unroll
        for (int i = 0; i < 16; ++i) f[i] = 0.f;
    }
#pragma unroll
    for (int h = 0; h < 2; ++h) {
        bfrag hv, lv;
#pragma unroll
        for (int j = 0; j < 8; ++j) {
            float x = f[h * 8 + j];
            ushort hb = f2bf(x);
            float r = x - bf2f(hb);
            hv[j] = (short)hb;
            lv[j] = (short)f2bf(r);
        }
        const int slot = (ks * 2 + (row >> 5)) * 64 + (row & 31) + 32 * h;
        *(bfrag*)&Ah[slot * 8] = hv;
        *(bfrag*)&Al[slot * 8] = lv;
    }
}

// Epilogue: wave-accs -> Ct(LDS) -> vectorized float4 stores.
// Math order identical to direct path: o = acc + bias; [gelu | +resid]; store.
template <int EPI>
__device__ __forceinline__ void epilogue(float* Ct, const f32x16& acc0,
                                         const f32x16& acc1, int t, int rblk,
                                         int ch, int l, int row0,
                                         const float* __restrict__ bias,
                                         const float* __restrict__ resid,
                                         float* __restrict__ C, int M) {
    __syncthreads();  // Ct aliases A/W LDS — all MFMA reads done
    {
        const int colbase = ch * 64 + (l & 31);
        const int rb = rblk * 32 + 4 * (l >> 5);
#pragma unroll
        for (int cf2 = 0; cf2 < 2; ++cf2) {
            const int col = colbase + cf2 * 32;
#pragma unroll
            for (int r = 0; r < 16; ++r) {
                const int rl = rb + (r & 3) + 8 * (r >> 2);
                Ct[rl * CTS + col] = (cf2 == 0 ? acc0[r] : acc1[r]);
            }
        }
    }
    __syncthreads();
    {
        const int rl = t >> 2, j = t & 3;
        const int grow = row0 + rl;
        if (grow < M) {
            float* cp = C + (size_t)grow * DIM;
            const float* rp = (EPI == EPI_RESID) ? resid + (size_t)grow * DIM : nullptr;
#pragma unroll
            for (int i = 0; i < 8; ++i) {
                const int c0 = (j + 4 * i) * 4;
                float4 v = *(const float4*)&Ct[rl * CTS + c0];
                const float4 b4 = *(const float4*)&bias[c0];
                v.x += b4.x; v.y += b4.y; v.z += b4.z; v.w += b4.w;
                if (EPI == EPI_GELU) {
                    v.x = gelu_f(v.x); v.y = gelu_f(v.y);
                    v.z = gelu_f(v.z); v.w = gelu_f(v.w);
                }
                if (EPI == EPI_RESID) {
                    const float4 r4 = *(const float4*)&rp[c0];
                    v.x += r4.x; v.y += r4.y; v.z += r4.z; v.w += r4.w;
                }
                *(float4*)&cp[c0] = v;
            }
        }
    }
    __syncthreads();  // Ct reuse safety for callers that continue
}

// Single GEMM: C[M,128] = epi(A @ W + bias)
template <int EPI>
__global__ __launch_bounds__(256)
void gemm_mfma(const float* __restrict__ A, const ushort* __restrict__ wpre,
               const float* __restrict__ bias, const float* __restrict__ resid,
               float* __restrict__ C, int M) {
    __shared__ char smem[49152];  // 48 KB
    ushort* Ah = (ushort*)smem;                    // 8 KB
    ushort* Al = (ushort*)(smem + 8192);           // 8 KB
    ushort* Wh = (ushort*)(smem + 16384);          // 16 KB
    ushort* Wl = (ushort*)(smem + 32768);          // 16 KB
    float* Ct = (float*)smem;                      // 33.8 KB alias (epilogue)

    const int t = threadIdx.x;
    const int row0 = blockIdx.x * 64;
    const int w = t >> 6, l = t & 63;
    const int rblk = w & 1, ch = w >> 1;

    f32x16 acc0, acc1;
#pragma unroll
    for (int i = 0; i < 16; ++i) { acc0[i] = 0.f; acc1[i] = 0.f; }

    for (int c = 0; c < 2; ++c) {
        stage_A(A, M, row0, c * 64, t, Ah, Al);
        {
            const float4* gh = (const float4*)(wpre + ((size_t)c * 2 + 0) * 1024 * 8);
            const float4* gl = (const float4*)(wpre + ((size_t)c * 2 + 1) * 1024 * 8);
            float4* sh = (float4*)Wh;
            float4* sl = (float4*)Wl;
#pragma unroll
            for (int i = 0; i < 4; ++i) {
                sh[i * 256 + t] = gh[i * 256 + t];
                sl[i * 256 + t] = gl[i * 256 + t];
            }
        }
        __syncthreads();
#pragma unroll
        for (int ks = 0; ks < 4; ++ks) {
            const bfrag ah = *(const bfrag*)&Ah[((ks * 2 + rblk) * 64 + l) * 8];
            const bfrag al = *(const bfrag*)&Al[((ks * 2 + rblk) * 64 + l) * 8];
#pragma unroll
            for (int q = 0; q < 2; ++q) {
                const int cf = ch * 2 + q;
                const bfrag bh = *(const bfrag*)&Wh[((ks * 4 + cf) * 64 + l) * 8];
                const bfrag bl = *(const bfrag*)&Wl[((ks * 4 + cf) * 64 + l) * 8];
                f32x16& acc = q == 0 ? acc0 : acc1;
                acc = __builtin_amdgcn_mfma_f32_32x32x16_bf16(al, bh, acc, 0, 0, 0);
                acc = __builtin_amdgcn_mfma_f32_32x32x16_bf16(ah, bl, acc, 0, 0, 0);
                acc = __builtin_amdgcn_mfma_f32_32x32x16_bf16(ah, bh, acc, 0, 0, 0);
            }
        }
        __syncthreads();
    }
    epilogue<EPI>(Ct, acc0, acc1, t, rblk, ch, l, row0, bias, resid, C, M);
}

// Fused K/Q GEMM: K = A@Wk+bk, Q = A@Wq+bq (one A staging).
__global__ __launch_bounds__(256)
void gemm_mfma_kq(const float* __restrict__ A, const ushort* __restrict__ wkpre,
                  const ushort* __restrict__ wqpre, const float* __restrict__ bkb,
                  const float* __restrict__ bqb, float* __restrict__ K,
                  float* __restrict__ Q, int M) {
    __shared__ char smem[81920];  // 80 KB
    ushort* Ah  = (ushort*)smem;                   // 8 KB
    ushort* Al  = (ushort*)(smem + 8192);          // 8 KB
    ushort* Wkh = (ushort*)(smem + 16384);         // 16 KB
    ushort* Wkl = (ushort*)(smem + 32768);         // 16 KB
    ushort* Wqh = (ushort*)(smem + 49152);         // 16 KB
    ushort* Wql = (ushort*)(smem + 65536);         // 16 KB
    float* Ct = (float*)smem;                      // 33.8 KB alias (epilogue)

    const int t = threadIdx.x;
    const int row0 = blockIdx.x * 64;
    const int w = t >> 6, l = t & 63;
    const int rblk = w & 1, ch = w >> 1;

    f32x16 ak0, ak1, aq0, aq1;
#pragma unroll
    for (int i = 0; i < 16; ++i) { ak0[i] = 0.f; ak1[i] = 0.f; aq0[i] = 0.f; aq1[i] = 0.f; }

    for (int c = 0; c < 2; ++c) {
        stage_A(A, M, row0, c * 64, t, Ah, Al);
        {
            const float4* gkh = (const float4*)(wkpre + ((size_t)c * 2 + 0) * 1024 * 8);
            const float4* gkl = (const float4*)(wkpre + ((size_t)c * 2 + 1) * 1024 * 8);
            const float4* gqh = (const float4*)(wqpre + ((size_t)c * 2 + 0) * 1024 * 8);
            const float4* gql = (const float4*)(wqpre + ((size_t)c * 2 + 1) * 1024 * 8);
            float4* skh = (float4*)Wkh;
            float4* skl = (float4*)Wkl;
            float4* sqh = (float4*)Wqh;
            float4* sql = (float4*)Wql;
#pragma unroll
            for (int i = 0; i < 4; ++i) {
                skh[i * 256 + t] = gkh[i * 256 + t];
                skl[i * 256 + t] = gkl[i * 256 + t];
                sqh[i * 256 + t] = gqh[i * 256 + t];
                sql[i * 256 + t] = gql[i * 256 + t];
            }
        }
        __syncthreads();
#pragma unroll
        for (int ks = 0; ks < 4; ++ks) {
            const bfrag ah = *(const bfrag*)&Ah[((ks * 2 + rblk) * 64 + l) * 8];
            const bfrag al = *(const bfrag*)&Al[((ks * 2 + rblk) * 64 + l) * 8];
#pragma unroll
            for (int q = 0; q < 2; ++q) {
                const int cf = ch * 2 + q;
                const int so = ((ks * 4 + cf) * 64 + l) * 8;
                {
                    const bfrag bh = *(const bfrag*)&Wkh[so];
                    const bfrag bl = *(const bfrag*)&Wkl[so];
                    f32x16& acc = q == 0 ? ak0 : ak1;
                    acc = __builtin_amdgcn_mfma_f32_32x32x16_bf16(al, bh, acc, 0, 0, 0);
                    acc = __builtin_amdgcn_mfma_f32_32x32x16_bf16(ah, bl, acc, 0, 0, 0);
                    acc = __builtin_amdgcn_mfma_f32_32x32x16_bf16(ah, bh, acc, 0, 0, 0);
                }
                {
                    const bfrag bh = *(const bfrag*)&Wqh[so];
                    const bfrag bl = *(const bfrag*)&Wql[so];
                    f32x16& acc = q == 0 ? aq0 : aq1;
                    acc = __builtin_amdgcn_mfma_f32_32x32x16_bf16(al, bh, acc, 0, 0, 0);
                    acc = __builtin_amdgcn_mfma_f32_32x32x16_bf16(ah, bl, acc, 0, 0, 0);
                    acc = __builtin_amdgcn_mfma_f32_32x32x16_bf16(ah, bh, acc, 0, 0, 0);
                }
            }
        }
        __syncthreads();
    }
    epilogue<EPI_NONE>(Ct, ak0, ak1, t, rblk, ch, l, row0, bkb, nullptr, K, M);
    epilogue<EPI_NONE>(Ct, aq0, aq1, t, rblk, ch, l, row0, bqb, nullptr, Q, M);
}

// ---------------- output projection ----------------
__global__ __launch_bounds__(256)
void out_kernel(const float* __restrict__ h, const float* __restrict__ Wout,
                const float* __restrict__ bout, float* __restrict__ out) {
    int tid = blockIdx.x * blockDim.x + threadIdx.x;
    int n = tid >> 5;
    if (n >= NN) return;
    int lane = tid & 31;
    const float4 h4 = *(const float4*)(h + (size_t)n * DIM + lane * 4);
    const float4 w4 = *(const float4*)(Wout + lane * 4);
    float s = h4.x * w4.x + h4.y * w4.y + h4.z * w4.z + h4.w * w4.w;
#pragma unroll
    for (int off = 16; off > 0; off >>= 1) s += __shfl_down(s, off, 32);
    if (lane == 0) out[n] = s + bout[0];
}

extern "C" void kernel_launch(void* const* d_in, const int* in_sizes, int n_in,
                              void* d_out, int out_size, void* d_ws, size_t ws_size,
                              hipStream_t stream) {
    const float* feats = (const float*)d_in[0];
    const int* esrc = (const int*)d_in[1];
    const int* edst = (const int*)d_in[2];
    const float* Win = (const float*)d_in[3];
    const float* bin_ = (const float*)d_in[4];
    const float* Wk = (const float*)d_in[5];
    const float* bk = (const float*)d_in[6];
    const float* Wq = (const float*)d_in[7];
    const float* bq = (const float*)d_in[8];
    const float* Wv = (const float*)d_in[9];
    const float* bv = (const float*)d_in[10];
    const float* Wl = (const float*)d_in[11];
    const float* bl = (const float*)d_in[12];
    const float* Wout = (const float*)d_in[13];
    const float* bout = (const float*)d_in[14];

    float* ws = (float*)d_ws;
    const size_t ND = (size_t)NN * DIM;
    float* h0 = ws;            // [N,D]
    float* h1 = ws + ND;       // [N,D]
    float* key = ws + 2 * ND;  // [N,D]
    float* qry = ws + 3 * ND;  // [N,D]  (agg writes in place — race-free per row)
    float* invdeg = ws + 4 * ND;                  // [N]
    int* deg = (int*)(ws + 4 * ND + NN);          // [N]
    int* rowptr = deg + NN;                       // [N+1]
    int* cursor = rowptr + NN + 1;                // [N]
    int* ebuf = cursor + NN;                      // [E]
    int* partial = ebuf + EE;                     // [NBLK]
    int* pofs = partial + NBLK;                   // [NBLK]
    size_t intofs = (size_t)((pofs + NBLK) - (int*)d_ws);
    intofs = (intofs + 3) & ~(size_t)3;
    ushort* pre = (ushort*)((int*)d_ws + intofs);  // 13 x 64 KB pre-split weights

    dim3 b256(256);
    const int GB = (NN + 63) / 64;   // 782 GEMM blocks
    const size_t WPM = 4 * 1024 * 8; // ushorts per pre-split matrix

    // ---- weight pre-split (once per launch) ----
    wsplit_kernel<<<26, b256, 0, stream>>>(Win, Wk, Wq, Wv, Wl, pre);

    // ---- CSR build ----
    hipMemsetAsync(deg, 0, NN * sizeof(int), stream);
    deg_kernel<<<(EE + 255) / 256, b256, 0, stream>>>(edst, deg);
    partial_kernel<<<NBLK, b256, 0, stream>>>(deg, partial);
    scanpart_kernel<<<1, b256, 0, stream>>>(partial, pofs);
    fill_kernel<<<NBLK, b256, 0, stream>>>(deg, pofs, rowptr, cursor, invdeg);
    bucket_kernel<<<(EE + 255) / 256, b256, 0, stream>>>(esrc, edst, cursor, ebuf);

    // h = gelu(feats @ Win + bin)
    gemm_mfma<EPI_GELU><<<GB, b256, 0, stream>>>(feats, pre, bin_, nullptr, h0, NN);

    const float* hin = h0;
    float* hout = h1;
    for (int i = 0; i < LL; ++i) {
        const ushort* wk = pre + (size_t)(1 + i) * WPM;
        const ushort* wq = pre + (size_t)(4 + i) * WPM;
        const ushort* wv = pre + (size_t)(7 + i) * WPM;
        const ushort* wl = pre + (size_t)(10 + i) * WPM;
        const float* bki = bk + (size_t)i * DIM;
        const float* bqi = bq + (size_t)i * DIM;
        const float* bvi = bv + (size_t)i * DIM;
        const float* bli = bl + (size_t)i * DIM;

        gemm_mfma_kq<<<GB, b256, 0, stream>>>(hin, wk, wq, bki, bqi, key, qry, NN);
        agg_kernel<<<(NN * 64) / 256, b256, 0, stream>>>(key, qry, rowptr, ebuf,
                                                         invdeg, qry);
        gemm_mfma<EPI_GELU><<<GB, b256, 0, stream>>>(qry, wv, bvi, nullptr, key, NN);
        gemm_mfma<EPI_RESID><<<GB, b256, 0, stream>>>(key, wl, bli, hin, hout, NN);
        float* tmp = (float*)hin;
        hin = hout;
        hout = tmp;
    }
    out_kernel<<<(NN * 32 + 255) / 256, b256, 0, stream>>>(hin, Wout, bout,
                                                           (float*)d_out);
}

// Round 12
// 501.728 us; speedup vs baseline: 1.8241x; 1.0705x over previous
//
#include <hip/hip_runtime.h>
#include <hip/hip_bf16.h>
#include <math.h>

#define NN 50000
#define EE 600000
#define DIM 128
#define LL 3
#define SCB 256
#define NBLK ((NN + SCB - 1) / SCB)   // 196
#define CTS 132                        // Ct row stride (floats)

typedef float f32x16 __attribute__((ext_vector_type(16)));
typedef short bfrag __attribute__((ext_vector_type(8)));   // 8 bf16 (4 VGPRs)

__device__ __forceinline__ float gelu_f(float x) {
    return 0.5f * x * (1.0f + erff(x * 0.70710678118654752440f));
}

__device__ __forceinline__ ushort f2bf(float x) {
    union { float f; uint u; } v; v.f = x;
    uint r = v.u + 0x7fffu + ((v.u >> 16) & 1u);  // RTN-even
    return (ushort)(r >> 16);
}
__device__ __forceinline__ float bf2f(ushort h) {
    union { uint u; float f; } v; v.u = ((uint)h) << 16;
    return v.f;
}

// ---------------- CSR build ----------------
__global__ __launch_bounds__(256) void deg_kernel(const int* __restrict__ dst,
                                                  int* __restrict__ deg) {
    int e = blockIdx.x * blockDim.x + threadIdx.x;
    if (e < EE) atomicAdd(&deg[dst[e]], 1);
}

__global__ __launch_bounds__(256)
void partial_kernel(const int* __restrict__ deg, int* __restrict__ partial) {
    __shared__ int s[256];
    const int t = threadIdx.x;
    const int n = blockIdx.x * SCB + t;
    s[t] = (n < NN) ? deg[n] : 0;
    __syncthreads();
#pragma unroll
    for (int off = 128; off > 0; off >>= 1) {
        if (t < off) s[t] += s[t + off];
        __syncthreads();
    }
    if (t == 0) partial[blockIdx.x] = s[0];
}

__global__ __launch_bounds__(256)
void scanpart_kernel(const int* __restrict__ partial, int* __restrict__ pofs) {
    __shared__ int s[256];
    const int t = threadIdx.x;
    const int own = (t < NBLK) ? partial[t] : 0;
    s[t] = own;
    __syncthreads();
#pragma unroll
    for (int off = 1; off < 256; off <<= 1) {
        int v = s[t];
        int a = (t >= off) ? s[t - off] : 0;
        __syncthreads();
        s[t] = v + a;
        __syncthreads();
    }
    if (t < NBLK) pofs[t] = s[t] - own;  // exclusive
}

__global__ __launch_bounds__(256)
void fill_kernel(const int* __restrict__ deg, const int* __restrict__ pofs,
                 int* __restrict__ rowptr, int* __restrict__ cursor,
                 float* __restrict__ invdeg) {
    __shared__ int s[256];
    const int t = threadIdx.x;
    const int n = blockIdx.x * SCB + t;
    const int d = (n < NN) ? deg[n] : 0;
    s[t] = d;
    __syncthreads();
#pragma unroll
    for (int off = 1; off < 256; off <<= 1) {
        int v = s[t];
        int a = (t >= off) ? s[t - off] : 0;
        __syncthreads();
        s[t] = v + a;
        __syncthreads();
    }
    const int base = pofs[blockIdx.x] + s[t] - d;  // exclusive prefix
    if (n < NN) {
        rowptr[n] = base;
        cursor[n] = base;
        invdeg[n] = 1.0f / (float)(d < 1 ? 1 : d);
        if (n == NN - 1) rowptr[NN] = base + d;  // == EE
    }
}

__global__ __launch_bounds__(256)
void bucket_kernel(const int* __restrict__ src, const int* __restrict__ dst,
                   int* __restrict__ cursor, int* __restrict__ ebuf) {
    int e = blockIdx.x * blockDim.x + threadIdx.x;
    if (e < EE) {
        int slot = atomicAdd(&cursor[dst[e]], 1);
        ebuf[slot] = src[e];
    }
}

// ---------------- weight pre-split: fp32 W -> bf16 hi/lo fragment slots --------
__global__ __launch_bounds__(256)
void wsplit_kernel(const float* __restrict__ Win, const float* __restrict__ Wk,
                   const float* __restrict__ Wq, const float* __restrict__ Wv,
                   const float* __restrict__ Wl, ushort* __restrict__ pre) {
    const int b = blockIdx.x;       // 26 blocks: (matrix m, chunk c)
    const int m = b >> 1, c = b & 1;
    const float* W;
    if (m == 0) W = Win;
    else if (m <= 3) W = Wk + (size_t)(m - 1) * DIM * DIM;
    else if (m <= 6) W = Wq + (size_t)(m - 4) * DIM * DIM;
    else if (m <= 9) W = Wv + (size_t)(m - 7) * DIM * DIM;
    else W = Wl + (size_t)(m - 10) * DIM * DIM;
    ushort* dst = pre + (size_t)m * (4 * 1024 * 8) + (size_t)c * (2 * 1024 * 8);

    const int t = threadIdx.x;
    const int kc0 = c * 64;
    const int n = t & 127, kh = t >> 7;
    const int cf = n >> 5;
#pragma unroll
    for (int g = 0; g < 4; ++g) {
        const int kl0 = kh * 32 + g * 8;
#pragma unroll
        for (int j = 0; j < 8; ++j) {
            float x = W[(size_t)(kc0 + kl0 + j) * DIM + n];
            ushort hb = f2bf(x);
            float r = x - bf2f(hb);
            const int ks = kl0 >> 4, half = (kl0 >> 3) & 1;
            const int slot = (ks * 4 + cf) * 64 + (n & 31) + 32 * half;
            dst[slot * 8 + j] = hb;                  // hi plane
            dst[1024 * 8 + slot * 8 + j] = f2bf(r);  // lo plane
        }
    }
}

// ---------------- CSR gather aggregation (4-wide, R8-proven) ----------------
__global__ __launch_bounds__(256)
void agg_kernel(const float* __restrict__ key, const float* qry,
                const int* __restrict__ rowptr, const int* __restrict__ ebuf,
                const float* __restrict__ invdeg, float* agg) {
    int tid = blockIdx.x * blockDim.x + threadIdx.x;
    int n = tid >> 6;
    if (n >= NN) return;
    int c = (tid & 63) << 1;
    const float2 q2 = *(const float2*)(qry + (size_t)n * DIM + c);
    float ax = 0.f, ay = 0.f;
    int j = rowptr[n];
    const int hi = rowptr[n + 1];
    for (; j + 4 <= hi; j += 4) {
        const int s0 = ebuf[j], s1 = ebuf[j + 1], s2 = ebuf[j + 2], s3 = ebuf[j + 3];
        const float2 k0 = *(const float2*)(key + (size_t)s0 * DIM + c);
        const float2 k1 = *(const float2*)(key + (size_t)s1 * DIM + c);
        const float2 k2 = *(const float2*)(key + (size_t)s2 * DIM + c);
        const float2 k3 = *(const float2*)(key + (size_t)s3 * DIM + c);
        ax += gelu_f(k0.x + q2.x); ay += gelu_f(k0.y + q2.y);
        ax += gelu_f(k1.x + q2.x); ay += gelu_f(k1.y + q2.y);
        ax += gelu_f(k2.x + q2.x); ay += gelu_f(k2.y + q2.y);
        ax += gelu_f(k3.x + q2.x); ay += gelu_f(k3.y + q2.y);
    }
    for (; j < hi; ++j) {
        const int s = ebuf[j];
        const float2 k2 = *(const float2*)(key + (size_t)s * DIM + c);
        ax += gelu_f(k2.x + q2.x);
        ay += gelu_f(k2.y + q2.y);
    }
    const float inv = invdeg[n];
    *(float2*)(agg + (size_t)n * DIM + c) = make_float2(ax * inv, ay * inv);
}

// ---------------- MFMA GEMM machinery ----------------
enum { EPI_NONE = 0, EPI_GELU = 1, EPI_RESID = 2 };

// Stage A chunk (64 rows x 64 k) as bf16 hi/lo fragment slots.
__device__ __forceinline__ void stage_A(const float* __restrict__ A, int M,
                                        int row0, int kc0, int t,
                                        ushort* Ah, ushort* Al) {
    const int row = t >> 2, ks = t & 3;
    const int grow = row0 + row;
    float f[16];
    if (grow < M) {
        const float* p = A + (size_t)grow * DIM + kc0 + ks * 16;
        float4 q0 = *(const float4*)(p + 0);
        float4 q1 = *(const float4*)(p + 4);
        float4 q2 = *(const float4*)(p + 8);
        float4 q3 = *(const float4*)(p + 12);
        f[0]=q0.x; f[1]=q0.y; f[2]=q0.z; f[3]=q0.w;
        f[4]=q1.x; f[5]=q1.y; f[6]=q1.z; f[7]=q1.w;
        f[8]=q2.x; f[9]=q2.y; f[10]=q2.z; f[11]=q2.w;
        f[12]=q3.x; f[13]=q3.y; f[14]=q3.z; f[15]=q3.w;
    } else {
#pragma unroll
        for (int i = 0; i < 16; ++i) f[i] = 0.f;
    }
#pragma unroll
    for (int h = 0; h < 2; ++h) {
        bfrag hv, lv;
#pragma unroll
        for (int j = 0; j < 8; ++j) {
            float x = f[h * 8 + j];
            ushort hb = f2bf(x);
            float r = x - bf2f(hb);
            hv[j] = (short)hb;
            lv[j] = (short)f2bf(r);
        }
        const int slot = (ks * 2 + (row >> 5)) * 64 + (row & 31) + 32 * h;
        *(bfrag*)&Ah[slot * 8] = hv;
        *(bfrag*)&Al[slot * 8] = lv;
    }
}

// W chunk load: flat float4 copy of pre-split slots into Wh/Wl.
__device__ __forceinline__ void stage_W(const ushort* __restrict__ wpre, int c,
                                        int t, ushort* Wh, ushort* Wl) {
    const float4* gh = (const float4*)(wpre + ((size_t)c * 2 + 0) * 1024 * 8);
    const float4* gl = (const float4*)(wpre + ((size_t)c * 2 + 1) * 1024 * 8);
    float4* sh = (float4*)Wh;
    float4* sl = (float4*)Wl;
#pragma unroll
    for (int i = 0; i < 4; ++i) {
        sh[i * 256 + t] = gh[i * 256 + t];
        sl[i * 256 + t] = gl[i * 256 + t];
    }
}

// Epilogue: wave-accs -> Ct(LDS) -> vectorized float4 stores.
template <int EPI>
__device__ __forceinline__ void epilogue(float* Ct, const f32x16& acc0,
                                         const f32x16& acc1, int t, int rblk,
                                         int ch, int l, int row0,
                                         const float* __restrict__ bias,
                                         const float* __restrict__ resid,
                                         float* __restrict__ C, int M) {
    __syncthreads();  // Ct aliases A/W LDS — all prior reads done
    {
        const int colbase = ch * 64 + (l & 31);
        const int rb = rblk * 32 + 4 * (l >> 5);
#pragma unroll
        for (int cf2 = 0; cf2 < 2; ++cf2) {
            const int col = colbase + cf2 * 32;
#pragma unroll
            for (int r = 0; r < 16; ++r) {
                const int rl = rb + (r & 3) + 8 * (r >> 2);
                Ct[rl * CTS + col] = (cf2 == 0 ? acc0[r] : acc1[r]);
            }
        }
    }
    __syncthreads();
    {
        const int rl = t >> 2, j = t & 3;
        const int grow = row0 + rl;
        if (grow < M) {
            float* cp = C + (size_t)grow * DIM;
            const float* rp = (EPI == EPI_RESID) ? resid + (size_t)grow * DIM : nullptr;
#pragma unroll
            for (int i = 0; i < 8; ++i) {
                const int c0 = (j + 4 * i) * 4;
                float4 v = *(const float4*)&Ct[rl * CTS + c0];
                const float4 b4 = *(const float4*)&bias[c0];
                v.x += b4.x; v.y += b4.y; v.z += b4.z; v.w += b4.w;
                if (EPI == EPI_GELU) {
                    v.x = gelu_f(v.x); v.y = gelu_f(v.y);
                    v.z = gelu_f(v.z); v.w = gelu_f(v.w);
                }
                if (EPI == EPI_RESID) {
                    const float4 r4 = *(const float4*)&rp[c0];
                    v.x += r4.x; v.y += r4.y; v.z += r4.z; v.w += r4.w;
                }
                *(float4*)&cp[c0] = v;
            }
        }
    }
    __syncthreads();
}

// Single GEMM: C[M,128] = epi(A @ W + bias)
template <int EPI>
__global__ __launch_bounds__(256)
void gemm_mfma(const float* __restrict__ A, const ushort* __restrict__ wpre,
               const float* __restrict__ bias, const float* __restrict__ resid,
               float* __restrict__ C, int M) {
    __shared__ char smem[49152];  // 48 KB
    ushort* Ah = (ushort*)smem;
    ushort* Al = (ushort*)(smem + 8192);
    ushort* Wh = (ushort*)(smem + 16384);
    ushort* Wl = (ushort*)(smem + 32768);
    float* Ct = (float*)smem;

    const int t = threadIdx.x;
    const int row0 = blockIdx.x * 64;
    const int w = t >> 6, l = t & 63;
    const int rblk = w & 1, ch = w >> 1;

    f32x16 acc0, acc1;
#pragma unroll
    for (int i = 0; i < 16; ++i) { acc0[i] = 0.f; acc1[i] = 0.f; }

    for (int c = 0; c < 2; ++c) {
        stage_A(A, M, row0, c * 64, t, Ah, Al);
        stage_W(wpre, c, t, Wh, Wl);
        __syncthreads();
#pragma unroll
        for (int ks = 0; ks < 4; ++ks) {
            const bfrag ah = *(const bfrag*)&Ah[((ks * 2 + rblk) * 64 + l) * 8];
            const bfrag al = *(const bfrag*)&Al[((ks * 2 + rblk) * 64 + l) * 8];
#pragma unroll
            for (int q = 0; q < 2; ++q) {
                const int cf = ch * 2 + q;
                const bfrag bh = *(const bfrag*)&Wh[((ks * 4 + cf) * 64 + l) * 8];
                const bfrag bl = *(const bfrag*)&Wl[((ks * 4 + cf) * 64 + l) * 8];
                f32x16& acc = q == 0 ? acc0 : acc1;
                acc = __builtin_amdgcn_mfma_f32_32x32x16_bf16(al, bh, acc, 0, 0, 0);
                acc = __builtin_amdgcn_mfma_f32_32x32x16_bf16(ah, bl, acc, 0, 0, 0);
                acc = __builtin_amdgcn_mfma_f32_32x32x16_bf16(ah, bh, acc, 0, 0, 0);
            }
        }
        __syncthreads();
    }
    epilogue<EPI>(Ct, acc0, acc1, t, rblk, ch, l, row0, bias, resid, C, M);
}

// Fused K/Q GEMM: K = A@Wk+bk, Q = A@Wq+bq (one A staging).
__global__ __launch_bounds__(256)
void gemm_mfma_kq(const float* __restrict__ A, const ushort* __restrict__ wkpre,
                  const ushort* __restrict__ wqpre, const float* __restrict__ bkb,
                  const float* __restrict__ bqb, float* __restrict__ K,
                  float* __restrict__ Q, int M) {
    __shared__ char smem[81920];  // 80 KB
    ushort* Ah  = (ushort*)smem;
    ushort* Al  = (ushort*)(smem + 8192);
    ushort* Wkh = (ushort*)(smem + 16384);
    ushort* Wkl = (ushort*)(smem + 32768);
    ushort* Wqh = (ushort*)(smem + 49152);
    ushort* Wql = (ushort*)(smem + 65536);
    float* Ct = (float*)smem;

    const int t = threadIdx.x;
    const int row0 = blockIdx.x * 64;
    const int w = t >> 6, l = t & 63;
    const int rblk = w & 1, ch = w >> 1;

    f32x16 ak0, ak1, aq0, aq1;
#pragma unroll
    for (int i = 0; i < 16; ++i) { ak0[i] = 0.f; ak1[i] = 0.f; aq0[i] = 0.f; aq1[i] = 0.f; }

    for (int c = 0; c < 2; ++c) {
        stage_A(A, M, row0, c * 64, t, Ah, Al);
        stage_W(wkpre, c, t, Wkh, Wkl);
        stage_W(wqpre, c, t, Wqh, Wql);
        __syncthreads();
#pragma unroll
        for (int ks = 0; ks < 4; ++ks) {
            const bfrag ah = *(const bfrag*)&Ah[((ks * 2 + rblk) * 64 + l) * 8];
            const bfrag al = *(const bfrag*)&Al[((ks * 2 + rblk) * 64 + l) * 8];
#pragma unroll
            for (int q = 0; q < 2; ++q) {
                const int cf = ch * 2 + q;
                const int so = ((ks * 4 + cf) * 64 + l) * 8;
                {
                    const bfrag bh = *(const bfrag*)&Wkh[so];
                    const bfrag bl = *(const bfrag*)&Wkl[so];
                    f32x16& acc = q == 0 ? ak0 : ak1;
                    acc = __builtin_amdgcn_mfma_f32_32x32x16_bf16(al, bh, acc, 0, 0, 0);
                    acc = __builtin_amdgcn_mfma_f32_32x32x16_bf16(ah, bl, acc, 0, 0, 0);
                    acc = __builtin_amdgcn_mfma_f32_32x32x16_bf16(ah, bh, acc, 0, 0, 0);
                }
                {
                    const bfrag bh = *(const bfrag*)&Wqh[so];
                    const bfrag bl = *(const bfrag*)&Wql[so];
                    f32x16& acc = q == 0 ? aq0 : aq1;
                    acc = __builtin_amdgcn_mfma_f32_32x32x16_bf16(al, bh, acc, 0, 0, 0);
                    acc = __builtin_amdgcn_mfma_f32_32x32x16_bf16(ah, bl, acc, 0, 0, 0);
                    acc = __builtin_amdgcn_mfma_f32_32x32x16_bf16(ah, bh, acc, 0, 0, 0);
                }
            }
        }
        __syncthreads();
    }
    epilogue<EPI_NONE>(Ct, ak0, ak1, t, rblk, ch, l, row0, bkb, nullptr, K, M);
    epilogue<EPI_NONE>(Ct, aq0, aq1, t, rblk, ch, l, row0, bqb, nullptr, Q, M);
}

// Fused V/L GEMM: t = gelu(A@Wv+bv) kept on-chip; C = t@Wl + bl + resid.
__global__ __launch_bounds__(256)
void gemm_mfma_vl(const float* __restrict__ A, const ushort* __restrict__ wvpre,
                  const ushort* __restrict__ wlpre, const float* __restrict__ bvb,
                  const float* __restrict__ blb, const float* __restrict__ resid,
                  float* __restrict__ C, int M) {
    __shared__ char smem[49152];  // 48 KB
    ushort* Ah = (ushort*)smem;
    ushort* Al = (ushort*)(smem + 8192);
    ushort* Wh = (ushort*)(smem + 16384);
    ushort* Wl = (ushort*)(smem + 32768);
    float* Ct = (float*)smem;

    const int t = threadIdx.x;
    const int row0 = blockIdx.x * 64;
    const int w = t >> 6, l = t & 63;
    const int rblk = w & 1, ch = w >> 1;

    f32x16 acc0, acc1;
#pragma unroll
    for (int i = 0; i < 16; ++i) { acc0[i] = 0.f; acc1[i] = 0.f; }

    // ---- phase 1: conv = A @ Wv ----
    for (int c = 0; c < 2; ++c) {
        stage_A(A, M, row0, c * 64, t, Ah, Al);
        stage_W(wvpre, c, t, Wh, Wl);
        __syncthreads();
#pragma unroll
        for (int ks = 0; ks < 4; ++ks) {
            const bfrag ah = *(const bfrag*)&Ah[((ks * 2 + rblk) * 64 + l) * 8];
            const bfrag al = *(const bfrag*)&Al[((ks * 2 + rblk) * 64 + l) * 8];
#pragma unroll
            for (int q = 0; q < 2; ++q) {
                const int cf = ch * 2 + q;
                const bfrag bh = *(const bfrag*)&Wh[((ks * 4 + cf) * 64 + l) * 8];
                const bfrag bl = *(const bfrag*)&Wl[((ks * 4 + cf) * 64 + l) * 8];
                f32x16& acc = q == 0 ? acc0 : acc1;
                acc = __builtin_amdgcn_mfma_f32_32x32x16_bf16(al, bh, acc, 0, 0, 0);
                acc = __builtin_amdgcn_mfma_f32_32x32x16_bf16(ah, bl, acc, 0, 0, 0);
                acc = __builtin_amdgcn_mfma_f32_32x32x16_bf16(ah, bh, acc, 0, 0, 0);
            }
        }
        __syncthreads();
    }
    // ---- t = gelu(conv + bv) -> Ct (aliases all staging LDS) ----
    {
        const int colbase = ch * 64 + (l & 31);
        const int rb = rblk * 32 + 4 * (l >> 5);
#pragma unroll
        for (int cf2 = 0; cf2 < 2; ++cf2) {
            const int col = colbase + cf2 * 32;
            const float bv = bvb[col];
#pragma unroll
            for (int r = 0; r < 16; ++r) {
                const int rl = rb + (r & 3) + 8 * (r >> 2);
                Ct[rl * CTS + col] = gelu_f((cf2 == 0 ? acc0[r] : acc1[r]) + bv);
            }
        }
    }
    __syncthreads();
    // ---- extract t's A-fragments from Ct directly into registers ----
    // lane l of wave rblk needs row = rblk*32+(l&31), k = c*64+ks*16+(l>>5)*8+j
    // (identical to stage_A slot semantics -> bitwise-identical fragments)
    bfrag tah[2][4], tal[2][4];
    {
        const int trow = rblk * 32 + (l & 31);
        const int khalf = (l >> 5) * 8;
#pragma unroll
        for (int c = 0; c < 2; ++c)
#pragma unroll
            for (int ks = 0; ks < 4; ++ks) {
                const float* p = &Ct[trow * CTS + c * 64 + ks * 16 + khalf];
                bfrag hv, lv;
#pragma unroll
                for (int j = 0; j < 8; ++j) {
                    float x = p[j];
                    ushort hb = f2bf(x);
                    float r = x - bf2f(hb);
                    hv[j] = (short)hb;
                    lv[j] = (short)f2bf(r);
                }
                tah[c][ks] = hv;
                tal[c][ks] = lv;
            }
    }
    __syncthreads();  // Ct dead; W region reusable
    // ---- phase 2: h = t @ Wl ----
    f32x16 bcc0, bcc1;
#pragma unroll
    for (int i = 0; i < 16; ++i) { bcc0[i] = 0.f; bcc1[i] = 0.f; }
    for (int c = 0; c < 2; ++c) {
        stage_W(wlpre, c, t, Wh, Wl);
        __syncthreads();
#pragma unroll
        for (int ks = 0; ks < 4; ++ks) {
            const bfrag ah = tah[c][ks];
            const bfrag al = tal[c][ks];
#pragma unroll
            for (int q = 0; q < 2; ++q) {
                const int cf = ch * 2 + q;
                const bfrag bh = *(const bfrag*)&Wh[((ks * 4 + cf) * 64 + l) * 8];
                const bfrag bl = *(const bfrag*)&Wl[((ks * 4 + cf) * 64 + l) * 8];
                f32x16& acc = q == 0 ? bcc0 : bcc1;
                acc = __builtin_amdgcn_mfma_f32_32x32x16_bf16(al, bh, acc, 0, 0, 0);
                acc = __builtin_amdgcn_mfma_f32_32x32x16_bf16(ah, bl, acc, 0, 0, 0);
                acc = __builtin_amdgcn_mfma_f32_32x32x16_bf16(ah, bh, acc, 0, 0, 0);
            }
        }
        __syncthreads();
    }
    epilogue<EPI_RESID>(Ct, bcc0, bcc1, t, rblk, ch, l, row0, blb, resid, C, M);
}

// ---------------- output projection ----------------
__global__ __launch_bounds__(256)
void out_kernel(const float* __restrict__ h, const float* __restrict__ Wout,
                const float* __restrict__ bout, float* __restrict__ out) {
    int tid = blockIdx.x * blockDim.x + threadIdx.x;
    int n = tid >> 5;
    if (n >= NN) return;
    int lane = tid & 31;
    const float4 h4 = *(const float4*)(h + (size_t)n * DIM + lane * 4);
    const float4 w4 = *(const float4*)(Wout + lane * 4);
    float s = h4.x * w4.x + h4.y * w4.y + h4.z * w4.z + h4.w * w4.w;
#pragma unroll
    for (int off = 16; off > 0; off >>= 1) s += __shfl_down(s, off, 32);
    if (lane == 0) out[n] = s + bout[0];
}

extern "C" void kernel_launch(void* const* d_in, const int* in_sizes, int n_in,
                              void* d_out, int out_size, void* d_ws, size_t ws_size,
                              hipStream_t stream) {
    const float* feats = (const float*)d_in[0];
    const int* esrc = (const int*)d_in[1];
    const int* edst = (const int*)d_in[2];
    const float* Win = (const float*)d_in[3];
    const float* bin_ = (const float*)d_in[4];
    const float* Wk = (const float*)d_in[5];
    const float* bk = (const float*)d_in[6];
    const float* Wq = (const float*)d_in[7];
    const float* bq = (const float*)d_in[8];
    const float* Wv = (const float*)d_in[9];
    const float* bv = (const float*)d_in[10];
    const float* Wl = (const float*)d_in[11];
    const float* bl = (const float*)d_in[12];
    const float* Wout = (const float*)d_in[13];
    const float* bout = (const float*)d_in[14];

    float* ws = (float*)d_ws;
    const size_t ND = (size_t)NN * DIM;
    float* h0 = ws;            // [N,D]
    float* h1 = ws + ND;       // [N,D]
    float* key = ws + 2 * ND;  // [N,D]
    float* qry = ws + 3 * ND;  // [N,D]  (agg writes in place — race-free per row)
    float* invdeg = ws + 4 * ND;                  // [N]
    int* deg = (int*)(ws + 4 * ND + NN);          // [N]
    int* rowptr = deg + NN;                       // [N+1]
    int* cursor = rowptr + NN + 1;                // [N]
    int* ebuf = cursor + NN;                      // [E]
    int* partial = ebuf + EE;                     // [NBLK]
    int* pofs = partial + NBLK;                   // [NBLK]
    size_t intofs = (size_t)((pofs + NBLK) - (int*)d_ws);
    intofs = (intofs + 3) & ~(size_t)3;
    ushort* pre = (ushort*)((int*)d_ws + intofs);  // 13 x 64 KB pre-split weights

    dim3 b256(256);
    const int GB = (NN + 63) / 64;   // 782 GEMM blocks
    const size_t WPM = 4 * 1024 * 8; // ushorts per pre-split matrix

    // ---- weight pre-split (once per launch) ----
    wsplit_kernel<<<26, b256, 0, stream>>>(Win, Wk, Wq, Wv, Wl, pre);

    // ---- CSR build ----
    hipMemsetAsync(deg, 0, NN * sizeof(int), stream);
    deg_kernel<<<(EE + 255) / 256, b256, 0, stream>>>(edst, deg);
    partial_kernel<<<NBLK, b256, 0, stream>>>(deg, partial);
    scanpart_kernel<<<1, b256, 0, stream>>>(partial, pofs);
    fill_kernel<<<NBLK, b256, 0, stream>>>(deg, pofs, rowptr, cursor, invdeg);
    bucket_kernel<<<(EE + 255) / 256, b256, 0, stream>>>(esrc, edst, cursor, ebuf);

    // h = gelu(feats @ Win + bin)
    gemm_mfma<EPI_GELU><<<GB, b256, 0, stream>>>(feats, pre, bin_, nullptr, h0, NN);

    const float* hin = h0;
    float* hout = h1;
    for (int i = 0; i < LL; ++i) {
        const ushort* wk = pre + (size_t)(1 + i) * WPM;
        const ushort* wq = pre + (size_t)(4 + i) * WPM;
        const ushort* wv = pre + (size_t)(7 + i) * WPM;
        const ushort* wl = pre + (size_t)(10 + i) * WPM;
        const float* bki = bk + (size_t)i * DIM;
        const float* bqi = bq + (size_t)i * DIM;
        const float* bvi = bv + (size_t)i * DIM;
        const float* bli = bl + (size_t)i * DIM;

        gemm_mfma_kq<<<GB, b256, 0, stream>>>(hin, wk, wq, bki, bqi, key, qry, NN);
        agg_kernel<<<(NN * 64) / 256, b256, 0, stream>>>(key, qry, rowptr, ebuf,
                                                         invdeg, qry);
        gemm_mfma_vl<<<GB, b256, 0, stream>>>(qry, wv, wl, bvi, bli, hin, hout, NN);
        float* tmp = (float*)hin;
        hin = hout;
        hout = tmp;
    }
    out_kernel<<<(NN * 32 + 255) / 256, b256, 0, stream>>>(hin, Wout, bout,
                                                           (float*)d_out);
}

// Round 13
// 496.505 us; speedup vs baseline: 1.8432x; 1.0105x over previous
//
#include <hip/hip_runtime.h>
#include <hip/hip_bf16.h>
#include <math.h>

#define NN 50000
#define EE 600000
#define DIM 128
#define LL 3
#define SCB 256
#define NBLK ((NN + SCB - 1) / SCB)   // 196
#define CTS 132                        // Ct row stride (floats)

typedef float f32x16 __attribute__((ext_vector_type(16)));
typedef short bfrag __attribute__((ext_vector_type(8)));   // 8 bf16 (4 VGPRs)

__device__ __forceinline__ float gelu_f(float x) {
    return 0.5f * x * (1.0f + erff(x * 0.70710678118654752440f));
}

__device__ __forceinline__ ushort f2bf(float x) {
    union { float f; uint u; } v; v.f = x;
    uint r = v.u + 0x7fffu + ((v.u >> 16) & 1u);  // RTN-even
    return (ushort)(r >> 16);
}
__device__ __forceinline__ float bf2f(ushort h) {
    union { uint u; float f; } v; v.u = ((uint)h) << 16;
    return v.f;
}

// ---------------- CSR build ----------------
__global__ __launch_bounds__(256) void deg_kernel(const int* __restrict__ dst,
                                                  int* __restrict__ deg) {
    int e = blockIdx.x * blockDim.x + threadIdx.x;
    if (e < EE) atomicAdd(&deg[dst[e]], 1);
}

__global__ __launch_bounds__(256)
void partial_kernel(const int* __restrict__ deg, int* __restrict__ partial) {
    __shared__ int s[256];
    const int t = threadIdx.x;
    const int n = blockIdx.x * SCB + t;
    s[t] = (n < NN) ? deg[n] : 0;
    __syncthreads();
#pragma unroll
    for (int off = 128; off > 0; off >>= 1) {
        if (t < off) s[t] += s[t + off];
        __syncthreads();
    }
    if (t == 0) partial[blockIdx.x] = s[0];
}

__global__ __launch_bounds__(256)
void scanpart_kernel(const int* __restrict__ partial, int* __restrict__ pofs) {
    __shared__ int s[256];
    const int t = threadIdx.x;
    const int own = (t < NBLK) ? partial[t] : 0;
    s[t] = own;
    __syncthreads();
#pragma unroll
    for (int off = 1; off < 256; off <<= 1) {
        int v = s[t];
        int a = (t >= off) ? s[t - off] : 0;
        __syncthreads();
        s[t] = v + a;
        __syncthreads();
    }
    if (t < NBLK) pofs[t] = s[t] - own;  // exclusive
}

__global__ __launch_bounds__(256)
void fill_kernel(const int* __restrict__ deg, const int* __restrict__ pofs,
                 int* __restrict__ rowptr, int* __restrict__ cursor,
                 float* __restrict__ invdeg) {
    __shared__ int s[256];
    const int t = threadIdx.x;
    const int n = blockIdx.x * SCB + t;
    const int d = (n < NN) ? deg[n] : 0;
    s[t] = d;
    __syncthreads();
#pragma unroll
    for (int off = 1; off < 256; off <<= 1) {
        int v = s[t];
        int a = (t >= off) ? s[t - off] : 0;
        __syncthreads();
        s[t] = v + a;
        __syncthreads();
    }
    const int base = pofs[blockIdx.x] + s[t] - d;  // exclusive prefix
    if (n < NN) {
        rowptr[n] = base;
        cursor[n] = base;
        invdeg[n] = 1.0f / (float)(d < 1 ? 1 : d);
        if (n == NN - 1) rowptr[NN] = base + d;  // == EE
    }
}

__global__ __launch_bounds__(256)
void bucket_kernel(const int* __restrict__ src, const int* __restrict__ dst,
                   int* __restrict__ cursor, int* __restrict__ ebuf) {
    int e = blockIdx.x * blockDim.x + threadIdx.x;
    if (e < EE) {
        int slot = atomicAdd(&cursor[dst[e]], 1);
        ebuf[slot] = src[e];
    }
}

// ---------------- weight pre-split: fp32 W -> bf16 hi/lo fragment slots --------
__global__ __launch_bounds__(256)
void wsplit_kernel(const float* __restrict__ Win, const float* __restrict__ Wk,
                   const float* __restrict__ Wq, const float* __restrict__ Wv,
                   const float* __restrict__ Wl, ushort* __restrict__ pre) {
    const int b = blockIdx.x;       // 26 blocks: (matrix m, chunk c)
    const int m = b >> 1, c = b & 1;
    const float* W;
    if (m == 0) W = Win;
    else if (m <= 3) W = Wk + (size_t)(m - 1) * DIM * DIM;
    else if (m <= 6) W = Wq + (size_t)(m - 4) * DIM * DIM;
    else if (m <= 9) W = Wv + (size_t)(m - 7) * DIM * DIM;
    else W = Wl + (size_t)(m - 10) * DIM * DIM;
    ushort* dst = pre + (size_t)m * (4 * 1024 * 8) + (size_t)c * (2 * 1024 * 8);

    const int t = threadIdx.x;
    const int kc0 = c * 64;
    const int n = t & 127, kh = t >> 7;
    const int cf = n >> 5;
#pragma unroll
    for (int g = 0; g < 4; ++g) {
        const int kl0 = kh * 32 + g * 8;
#pragma unroll
        for (int j = 0; j < 8; ++j) {
            float x = W[(size_t)(kc0 + kl0 + j) * DIM + n];
            ushort hb = f2bf(x);
            float r = x - bf2f(hb);
            const int ks = kl0 >> 4, half = (kl0 >> 3) & 1;
            const int slot = (ks * 4 + cf) * 64 + (n & 31) + 32 * half;
            dst[slot * 8 + j] = hb;                  // hi plane
            dst[1024 * 8 + slot * 8 + j] = f2bf(r);  // lo plane
        }
    }
}

// ---------------- CSR gather aggregation (4-wide, R8-proven) ----------------
__global__ __launch_bounds__(256)
void agg_kernel(const float* __restrict__ key, const float* qry,
                const int* __restrict__ rowptr, const int* __restrict__ ebuf,
                const float* __restrict__ invdeg, float* agg) {
    int tid = blockIdx.x * blockDim.x + threadIdx.x;
    int n = tid >> 6;
    if (n >= NN) return;
    int c = (tid & 63) << 1;
    const float2 q2 = *(const float2*)(qry + (size_t)n * DIM + c);
    float ax = 0.f, ay = 0.f;
    int j = rowptr[n];
    const int hi = rowptr[n + 1];
    for (; j + 4 <= hi; j += 4) {
        const int s0 = ebuf[j], s1 = ebuf[j + 1], s2 = ebuf[j + 2], s3 = ebuf[j + 3];
        const float2 k0 = *(const float2*)(key + (size_t)s0 * DIM + c);
        const float2 k1 = *(const float2*)(key + (size_t)s1 * DIM + c);
        const float2 k2 = *(const float2*)(key + (size_t)s2 * DIM + c);
        const float2 k3 = *(const float2*)(key + (size_t)s3 * DIM + c);
        ax += gelu_f(k0.x + q2.x); ay += gelu_f(k0.y + q2.y);
        ax += gelu_f(k1.x + q2.x); ay += gelu_f(k1.y + q2.y);
        ax += gelu_f(k2.x + q2.x); ay += gelu_f(k2.y + q2.y);
        ax += gelu_f(k3.x + q2.x); ay += gelu_f(k3.y + q2.y);
    }
    for (; j < hi; ++j) {
        const int s = ebuf[j];
        const float2 k2 = *(const float2*)(key + (size_t)s * DIM + c);
        ax += gelu_f(k2.x + q2.x);
        ay += gelu_f(k2.y + q2.y);
    }
    const float inv = invdeg[n];
    *(float2*)(agg + (size_t)n * DIM + c) = make_float2(ax * inv, ay * inv);
}

// ---------------- MFMA GEMM machinery ----------------
enum { EPI_NONE = 0, EPI_GELU = 1, EPI_RESID = 2 };

// Convert 16 A values (held in regs) to bf16 hi/lo fragment slots in LDS.
__device__ __forceinline__ void conv_A(const float4& q0, const float4& q1,
                                       const float4& q2, const float4& q3,
                                       int t, ushort* Ah, ushort* Al) {
    const int row = t >> 2, ks = t & 3;
    float f[16];
    f[0]=q0.x; f[1]=q0.y; f[2]=q0.z; f[3]=q0.w;
    f[4]=q1.x; f[5]=q1.y; f[6]=q1.z; f[7]=q1.w;
    f[8]=q2.x; f[9]=q2.y; f[10]=q2.z; f[11]=q2.w;
    f[12]=q3.x; f[13]=q3.y; f[14]=q3.z; f[15]=q3.w;
#pragma unroll
    for (int h = 0; h < 2; ++h) {
        bfrag hv, lv;
#pragma unroll
        for (int j = 0; j < 8; ++j) {
            float x = f[h * 8 + j];
            ushort hb = f2bf(x);
            float r = x - bf2f(hb);
            hv[j] = (short)hb;
            lv[j] = (short)f2bf(r);
        }
        const int slot = (ks * 2 + (row >> 5)) * 64 + (row & 31) + 32 * h;
        *(bfrag*)&Ah[slot * 8] = hv;
        *(bfrag*)&Al[slot * 8] = lv;
    }
}

// W chunk load: flat float4 copy of pre-split slots into Wh/Wl.
__device__ __forceinline__ void stage_W(const ushort* __restrict__ wpre, int c,
                                        int t, ushort* Wh, ushort* Wl) {
    const float4* gh = (const float4*)(wpre + ((size_t)c * 2 + 0) * 1024 * 8);
    const float4* gl = (const float4*)(wpre + ((size_t)c * 2 + 1) * 1024 * 8);
    float4* sh = (float4*)Wh;
    float4* sl = (float4*)Wl;
#pragma unroll
    for (int i = 0; i < 4; ++i) {
        sh[i * 256 + t] = gh[i * 256 + t];
        sl[i * 256 + t] = gl[i * 256 + t];
    }
}

// 3-term hi/lo split MFMA accumulate for one column-fragment.
__device__ __forceinline__ void mma3(f32x16& acc, const bfrag& ah, const bfrag& al,
                                     const ushort* Wh, const ushort* Wl, int so) {
    const bfrag bh = *(const bfrag*)&Wh[so];
    const bfrag bl = *(const bfrag*)&Wl[so];
    acc = __builtin_amdgcn_mfma_f32_32x32x16_bf16(al, bh, acc, 0, 0, 0);
    acc = __builtin_amdgcn_mfma_f32_32x32x16_bf16(ah, bl, acc, 0, 0, 0);
    acc = __builtin_amdgcn_mfma_f32_32x32x16_bf16(ah, bh, acc, 0, 0, 0);
}

// Epilogue: wave-accs -> Ct(LDS) -> vectorized float4 stores.
template <int EPI>
__device__ __forceinline__ void epilogue(float* Ct, const f32x16& acc0,
                                         const f32x16& acc1, int t, int rblk,
                                         int ch, int l, int row0,
                                         const float* __restrict__ bias,
                                         const float* __restrict__ resid,
                                         float* __restrict__ C, int M) {
    __syncthreads();  // Ct aliases A/W LDS — all prior reads done
    {
        const int colbase = ch * 64 + (l & 31);
        const int rb = rblk * 32 + 4 * (l >> 5);
#pragma unroll
        for (int cf2 = 0; cf2 < 2; ++cf2) {
            const int col = colbase + cf2 * 32;
#pragma unroll
            for (int r = 0; r < 16; ++r) {
                const int rl = rb + (r & 3) + 8 * (r >> 2);
                Ct[rl * CTS + col] = (cf2 == 0 ? acc0[r] : acc1[r]);
            }
        }
    }
    __syncthreads();
    {
        const int rl = t >> 2, j = t & 3;
        const int grow = row0 + rl;
        if (grow < M) {
            float* cp = C + (size_t)grow * DIM;
            const float* rp = (EPI == EPI_RESID) ? resid + (size_t)grow * DIM : nullptr;
#pragma unroll
            for (int i = 0; i < 8; ++i) {
                const int c0 = (j + 4 * i) * 4;
                float4 v = *(const float4*)&Ct[rl * CTS + c0];
                const float4 b4 = *(const float4*)&bias[c0];
                v.x += b4.x; v.y += b4.y; v.z += b4.z; v.w += b4.w;
                if (EPI == EPI_GELU) {
                    v.x = gelu_f(v.x); v.y = gelu_f(v.y);
                    v.z = gelu_f(v.z); v.w = gelu_f(v.w);
                }
                if (EPI == EPI_RESID) {
                    const float4 r4 = *(const float4*)&rp[c0];
                    v.x += r4.x; v.y += r4.y; v.z += r4.z; v.w += r4.w;
                }
                *(float4*)&cp[c0] = v;
            }
        }
    }
    __syncthreads();
}

// Single GEMM: C[M,128] = epi(A @ W + bias).  A-reg prefetch across chunks.
template <int EPI>
__global__ __launch_bounds__(256, 3)
void gemm_mfma(const float* __restrict__ A, const ushort* __restrict__ wpre,
               const float* __restrict__ bias, const float* __restrict__ resid,
               float* __restrict__ C, int M) {
    __shared__ char smem[49152];  // 48 KB
    ushort* Ah = (ushort*)smem;
    ushort* Al = (ushort*)(smem + 8192);
    ushort* Wh = (ushort*)(smem + 16384);
    ushort* Wl = (ushort*)(smem + 32768);
    float* Ct = (float*)smem;

    const int t = threadIdx.x;
    const int row0 = blockIdx.x * 64;
    const int w = t >> 6, l = t & 63;
    const int rblk = w & 1, ch = w >> 1;

    const bool aok = (row0 + (t >> 2)) < M;
    const float* aptr = A + (size_t)(row0 + (t >> 2)) * DIM + (t & 3) * 16;
    float4 a0 = {0,0,0,0}, a1 = a0, a2 = a0, a3 = a0;
    if (aok) {
        a0 = *(const float4*)(aptr + 0);  a1 = *(const float4*)(aptr + 4);
        a2 = *(const float4*)(aptr + 8);  a3 = *(const float4*)(aptr + 12);
    }

    f32x16 acc0, acc1;
#pragma unroll
    for (int i = 0; i < 16; ++i) { acc0[i] = 0.f; acc1[i] = 0.f; }

    for (int c = 0; c < 2; ++c) {
        conv_A(a0, a1, a2, a3, t, Ah, Al);
        stage_W(wpre, c, t, Wh, Wl);
        __syncthreads();
        if (c == 0 && aok) {  // prefetch chunk 1 under chunk-0 MFMA
            a0 = *(const float4*)(aptr + 64); a1 = *(const float4*)(aptr + 68);
            a2 = *(const float4*)(aptr + 72); a3 = *(const float4*)(aptr + 76);
        }
#pragma unroll
        for (int ks = 0; ks < 4; ++ks) {
            const bfrag ah = *(const bfrag*)&Ah[((ks * 2 + rblk) * 64 + l) * 8];
            const bfrag al = *(const bfrag*)&Al[((ks * 2 + rblk) * 64 + l) * 8];
            mma3(acc0, ah, al, Wh, Wl, ((ks * 4 + ch * 2 + 0) * 64 + l) * 8);
            mma3(acc1, ah, al, Wh, Wl, ((ks * 4 + ch * 2 + 1) * 64 + l) * 8);
        }
        __syncthreads();
    }
    epilogue<EPI>(Ct, acc0, acc1, t, rblk, ch, l, row0, bias, resid, C, M);
}

// Fused K/Q GEMM, 48 KB: W buffer time-shared between Wk and Wq per chunk.
__global__ __launch_bounds__(256, 3)
void gemm_mfma_kq(const float* __restrict__ A, const ushort* __restrict__ wkpre,
                  const ushort* __restrict__ wqpre, const float* __restrict__ bkb,
                  const float* __restrict__ bqb, float* __restrict__ K,
                  float* __restrict__ Q, int M) {
    __shared__ char smem[49152];  // 48 KB -> 3 blocks/CU (was 80 KB -> 2)
    ushort* Ah = (ushort*)smem;
    ushort* Al = (ushort*)(smem + 8192);
    ushort* Wh = (ushort*)(smem + 16384);
    ushort* Wl = (ushort*)(smem + 32768);
    float* Ct = (float*)smem;

    const int t = threadIdx.x;
    const int row0 = blockIdx.x * 64;
    const int w = t >> 6, l = t & 63;
    const int rblk = w & 1, ch = w >> 1;

    const bool aok = (row0 + (t >> 2)) < M;
    const float* aptr = A + (size_t)(row0 + (t >> 2)) * DIM + (t & 3) * 16;
    float4 a0 = {0,0,0,0}, a1 = a0, a2 = a0, a3 = a0;
    if (aok) {
        a0 = *(const float4*)(aptr + 0);  a1 = *(const float4*)(aptr + 4);
        a2 = *(const float4*)(aptr + 8);  a3 = *(const float4*)(aptr + 12);
    }

    f32x16 ak0, ak1, aq0, aq1;
#pragma unroll
    for (int i = 0; i < 16; ++i) { ak0[i] = 0.f; ak1[i] = 0.f; aq0[i] = 0.f; aq1[i] = 0.f; }

    for (int c = 0; c < 2; ++c) {
        conv_A(a0, a1, a2, a3, t, Ah, Al);
        stage_W(wkpre, c, t, Wh, Wl);
        __syncthreads();
        if (c == 0 && aok) {  // prefetch chunk 1 under K-MFMA
            a0 = *(const float4*)(aptr + 64); a1 = *(const float4*)(aptr + 68);
            a2 = *(const float4*)(aptr + 72); a3 = *(const float4*)(aptr + 76);
        }
#pragma unroll
        for (int ks = 0; ks < 4; ++ks) {
            const bfrag ah = *(const bfrag*)&Ah[((ks * 2 + rblk) * 64 + l) * 8];
            const bfrag al = *(const bfrag*)&Al[((ks * 2 + rblk) * 64 + l) * 8];
            mma3(ak0, ah, al, Wh, Wl, ((ks * 4 + ch * 2 + 0) * 64 + l) * 8);
            mma3(ak1, ah, al, Wh, Wl, ((ks * 4 + ch * 2 + 1) * 64 + l) * 8);
        }
        __syncthreads();
        stage_W(wqpre, c, t, Wh, Wl);   // reuse W buffer for Q weights
        __syncthreads();
#pragma unroll
        for (int ks = 0; ks < 4; ++ks) {
            const bfrag ah = *(const bfrag*)&Ah[((ks * 2 + rblk) * 64 + l) * 8];
            const bfrag al = *(const bfrag*)&Al[((ks * 2 + rblk) * 64 + l) * 8];
            mma3(aq0, ah, al, Wh, Wl, ((ks * 4 + ch * 2 + 0) * 64 + l) * 8);
            mma3(aq1, ah, al, Wh, Wl, ((ks * 4 + ch * 2 + 1) * 64 + l) * 8);
        }
        __syncthreads();
    }
    epilogue<EPI_NONE>(Ct, ak0, ak1, t, rblk, ch, l, row0, bkb, nullptr, K, M);
    epilogue<EPI_NONE>(Ct, aq0, aq1, t, rblk, ch, l, row0, bqb, nullptr, Q, M);
}

// Fused V/L GEMM: t = gelu(A@Wv+bv) kept on-chip; C = t@Wl + bl + resid.
__global__ __launch_bounds__(256, 3)
void gemm_mfma_vl(const float* __restrict__ A, const ushort* __restrict__ wvpre,
                  const ushort* __restrict__ wlpre, const float* __restrict__ bvb,
                  const float* __restrict__ blb, const float* __restrict__ resid,
                  float* __restrict__ C, int M) {
    __shared__ char smem[49152];  // 48 KB
    ushort* Ah = (ushort*)smem;
    ushort* Al = (ushort*)(smem + 8192);
    ushort* Wh = (ushort*)(smem + 16384);
    ushort* Wl = (ushort*)(smem + 32768);
    float* Ct = (float*)smem;

    const int t = threadIdx.x;
    const int row0 = blockIdx.x * 64;
    const int w = t >> 6, l = t & 63;
    const int rblk = w & 1, ch = w >> 1;

    const bool aok = (row0 + (t >> 2)) < M;
    const float* aptr = A + (size_t)(row0 + (t >> 2)) * DIM + (t & 3) * 16;
    float4 a0 = {0,0,0,0}, a1 = a0, a2 = a0, a3 = a0;
    if (aok) {
        a0 = *(const float4*)(aptr + 0);  a1 = *(const float4*)(aptr + 4);
        a2 = *(const float4*)(aptr + 8);  a3 = *(const float4*)(aptr + 12);
    }

    f32x16 acc0, acc1;
#pragma unroll
    for (int i = 0; i < 16; ++i) { acc0[i] = 0.f; acc1[i] = 0.f; }

    // ---- phase 1: conv = A @ Wv ----
    for (int c = 0; c < 2; ++c) {
        conv_A(a0, a1, a2, a3, t, Ah, Al);
        stage_W(wvpre, c, t, Wh, Wl);
        __syncthreads();
        if (c == 0 && aok) {
            a0 = *(const float4*)(aptr + 64); a1 = *(const float4*)(aptr + 68);
            a2 = *(const float4*)(aptr + 72); a3 = *(const float4*)(aptr + 76);
        }
#pragma unroll
        for (int ks = 0; ks < 4; ++ks) {
            const bfrag ah = *(const bfrag*)&Ah[((ks * 2 + rblk) * 64 + l) * 8];
            const bfrag al = *(const bfrag*)&Al[((ks * 2 + rblk) * 64 + l) * 8];
            mma3(acc0, ah, al, Wh, Wl, ((ks * 4 + ch * 2 + 0) * 64 + l) * 8);
            mma3(acc1, ah, al, Wh, Wl, ((ks * 4 + ch * 2 + 1) * 64 + l) * 8);
        }
        __syncthreads();
    }
    // ---- t = gelu(conv + bv) -> Ct (aliases all staging LDS) ----
    {
        const int colbase = ch * 64 + (l & 31);
        const int rb = rblk * 32 + 4 * (l >> 5);
#pragma unroll
        for (int cf2 = 0; cf2 < 2; ++cf2) {
            const int col = colbase + cf2 * 32;
            const float bv = bvb[col];
#pragma unroll
            for (int r = 0; r < 16; ++r) {
                const int rl = rb + (r & 3) + 8 * (r >> 2);
                Ct[rl * CTS + col] = gelu_f((cf2 == 0 ? acc0[r] : acc1[r]) + bv);
            }
        }
    }
    __syncthreads();
    // ---- extract t's A-fragments from Ct directly into registers ----
    bfrag tah[2][4], tal[2][4];
    {
        const int trow = rblk * 32 + (l & 31);
        const int khalf = (l >> 5) * 8;
#pragma unroll
        for (int c = 0; c < 2; ++c)
#pragma unroll
            for (int ks = 0; ks < 4; ++ks) {
                const float* p = &Ct[trow * CTS + c * 64 + ks * 16 + khalf];
                bfrag hv, lv;
#pragma unroll
                for (int j = 0; j < 8; ++j) {
                    float x = p[j];
                    ushort hb = f2bf(x);
                    float r = x - bf2f(hb);
                    hv[j] = (short)hb;
                    lv[j] = (short)f2bf(r);
                }
                tah[c][ks] = hv;
                tal[c][ks] = lv;
            }
    }
    __syncthreads();  // Ct dead; W region reusable
    // ---- phase 2: h = t @ Wl ----
    f32x16 bcc0, bcc1;
#pragma unroll
    for (int i = 0; i < 16; ++i) { bcc0[i] = 0.f; bcc1[i] = 0.f; }
    for (int c = 0; c < 2; ++c) {
        stage_W(wlpre, c, t, Wh, Wl);
        __syncthreads();
#pragma unroll
        for (int ks = 0; ks < 4; ++ks) {
            mma3(bcc0, tah[c][ks], tal[c][ks], Wh, Wl, ((ks * 4 + ch * 2 + 0) * 64 + l) * 8);
            mma3(bcc1, tah[c][ks], tal[c][ks], Wh, Wl, ((ks * 4 + ch * 2 + 1) * 64 + l) * 8);
        }
        __syncthreads();
    }
    epilogue<EPI_RESID>(Ct, bcc0, bcc1, t, rblk, ch, l, row0, blb, resid, C, M);
}

// ---------------- output projection ----------------
__global__ __launch_bounds__(256)
void out_kernel(const float* __restrict__ h, const float* __restrict__ Wout,
                const float* __restrict__ bout, float* __restrict__ out) {
    int tid = blockIdx.x * blockDim.x + threadIdx.x;
    int n = tid >> 5;
    if (n >= NN) return;
    int lane = tid & 31;
    const float4 h4 = *(const float4*)(h + (size_t)n * DIM + lane * 4);
    const float4 w4 = *(const float4*)(Wout + lane * 4);
    float s = h4.x * w4.x + h4.y * w4.y + h4.z * w4.z + h4.w * w4.w;
#pragma unroll
    for (int off = 16; off > 0; off >>= 1) s += __shfl_down(s, off, 32);
    if (lane == 0) out[n] = s + bout[0];
}

extern "C" void kernel_launch(void* const* d_in, const int* in_sizes, int n_in,
                              void* d_out, int out_size, void* d_ws, size_t ws_size,
                              hipStream_t stream) {
    const float* feats = (const float*)d_in[0];
    const int* esrc = (const int*)d_in[1];
    const int* edst = (const int*)d_in[2];
    const float* Win = (const float*)d_in[3];
    const float* bin_ = (const float*)d_in[4];
    const float* Wk = (const float*)d_in[5];
    const float* bk = (const float*)d_in[6];
    const float* Wq = (const float*)d_in[7];
    const float* bq = (const float*)d_in[8];
    const float* Wv = (const float*)d_in[9];
    const float* bv = (const float*)d_in[10];
    const float* Wl = (const float*)d_in[11];
    const float* bl = (const float*)d_in[12];
    const float* Wout = (const float*)d_in[13];
    const float* bout = (const float*)d_in[14];

    float* ws = (float*)d_ws;
    const size_t ND = (size_t)NN * DIM;
    float* h0 = ws;            // [N,D]
    float* h1 = ws + ND;       // [N,D]
    float* key = ws + 2 * ND;  // [N,D]
    float* qry = ws + 3 * ND;  // [N,D]  (agg writes in place — race-free per row)
    float* invdeg = ws + 4 * ND;                  // [N]
    int* deg = (int*)(ws + 4 * ND + NN);          // [N]
    int* rowptr = deg + NN;                       // [N+1]
    int* cursor = rowptr + NN + 1;                // [N]
    int* ebuf = cursor + NN;                      // [E]
    int* partial = ebuf + EE;                     // [NBLK]
    int* pofs = partial + NBLK;                   // [NBLK]
    size_t intofs = (size_t)((pofs + NBLK) - (int*)d_ws);
    intofs = (intofs + 3) & ~(size_t)3;
    ushort* pre = (ushort*)((int*)d_ws + intofs);  // 13 x 64 KB pre-split weights

    dim3 b256(256);
    const int GB = (NN + 63) / 64;   // 782 GEMM blocks
    const size_t WPM = 4 * 1024 * 8; // ushorts per pre-split matrix

    // ---- weight pre-split (once per launch) ----
    wsplit_kernel<<<26, b256, 0, stream>>>(Win, Wk, Wq, Wv, Wl, pre);

    // ---- CSR build ----
    hipMemsetAsync(deg, 0, NN * sizeof(int), stream);
    deg_kernel<<<(EE + 255) / 256, b256, 0, stream>>>(edst, deg);
    partial_kernel<<<NBLK, b256, 0, stream>>>(deg, partial);
    scanpart_kernel<<<1, b256, 0, stream>>>(partial, pofs);
    fill_kernel<<<NBLK, b256, 0, stream>>>(deg, pofs, rowptr, cursor, invdeg);
    bucket_kernel<<<(EE + 255) / 256, b256, 0, stream>>>(esrc, edst, cursor, ebuf);

    // h = gelu(feats @ Win + bin)
    gemm_mfma<EPI_GELU><<<GB, b256, 0, stream>>>(feats, pre, bin_, nullptr, h0, NN);

    const float* hin = h0;
    float* hout = h1;
    for (int i = 0; i < LL; ++i) {
        const ushort* wk = pre + (size_t)(1 + i) * WPM;
        const ushort* wq = pre + (size_t)(4 + i) * WPM;
        const ushort* wv = pre + (size_t)(7 + i) * WPM;
        const ushort* wl = pre + (size_t)(10 + i) * WPM;
        const float* bki = bk + (size_t)i * DIM;
        const float* bqi = bq + (size_t)i * DIM;
        const float* bvi = bv + (size_t)i * DIM;
        const float* bli = bl + (size_t)i * DIM;

        gemm_mfma_kq<<<GB, b256, 0, stream>>>(hin, wk, wq, bki, bqi, key, qry, NN);
        agg_kernel<<<(NN * 64) / 256, b256, 0, stream>>>(key, qry, rowptr, ebuf,
                                                         invdeg, qry);
        gemm_mfma_vl<<<GB, b256, 0, stream>>>(qry, wv, wl, bvi, bli, hin, hout, NN);
        float* tmp = (float*)hin;
        hin = hout;
        hout = tmp;
    }
    out_kernel<<<(NN * 32 + 255) / 256, b256, 0, stream>>>(hin, Wout, bout,
                                                           (float*)d_out);
}